// Round 14
// baseline (1766.910 us; speedup 1.0000x reference)
//
#include <hip/hip_runtime.h>
#include <hip/hip_bf16.h>
#include <math.h>

// Problem constants
#define NB 8
#define NSEQ 1024
#define M_ 1025                 // NSEQ + 1 (cls)
#define ROWS (NB * M_)          // 8200
#define DIMC 128
#define NHEADS 8
#define QKV3 3072               // 3*8*128
#define PEROWS (NB * NSEQ)      // 8192
#define ACS 1088                // vt padded column stride

typedef __attribute__((ext_vector_type(8))) short bf16x8;
typedef __attribute__((ext_vector_type(4))) float f32x4;

__device__ __forceinline__ float gelu_f(float x) {
  return 0.5f * x * (1.f + erff(x * 0.70710678118654752440f));
}

__device__ __forceinline__ unsigned short f2bf(float f) {
  __hip_bfloat16 h = __float2bfloat16(f);
  return *reinterpret_cast<unsigned short*>(&h);
}

__device__ __forceinline__ float bf2f(unsigned short u) {
  union { unsigned int i; float f; } c;
  c.i = ((unsigned int)u) << 16;
  return c.f;
}

// ---------------------------------------------------------------------------
// Fused PE encoder (R12)
// ---------------------------------------------------------------------------
__global__ __launch_bounds__(128) void pe_fused_k(
    const float* __restrict__ nf, const float* __restrict__ lp,
    const float* __restrict__ w1, const float* __restrict__ b1,
    const float* __restrict__ w2, const float* __restrict__ b2,
    const float* __restrict__ w3, const float* __restrict__ b3,
    const float* __restrict__ lng, const float* __restrict__ lnb,
    const float* __restrict__ w4, const float* __restrict__ b4,
    float* __restrict__ x)
{
  __shared__ float sA[16][36];
  __shared__ float sB[16][72];
  __shared__ float sC[16][72];
  const int tid = threadIdx.x;
  const int r0 = blockIdx.x * 16;

  for (int i = tid; i < 16 * 35; i += 128) {
    const int r = i / 35, c = i - r * 35;
    const int gr = r0 + r;
    sA[r][c] = (c < 3) ? nf[(size_t)gr * 3 + c] : lp[(size_t)gr * 32 + (c - 3)];
  }
  __syncthreads();
  if (tid < 70) {
    float acc[16];
#pragma unroll
    for (int r = 0; r < 16; ++r) acc[r] = b1[tid];
    for (int k = 0; k < 35; ++k) {
      const float wv = w1[k * 70 + tid];
#pragma unroll
      for (int r = 0; r < 16; ++r) acc[r] = fmaf(sA[r][k], wv, acc[r]);
    }
#pragma unroll
    for (int r = 0; r < 16; ++r) sB[r][tid] = gelu_f(acc[r]);
  }
  __syncthreads();
  if (tid < 70) {
    float acc[16];
#pragma unroll
    for (int r = 0; r < 16; ++r) acc[r] = b2[tid];
    for (int k = 0; k < 70; ++k) {
      const float wv = w2[k * 70 + tid];
#pragma unroll
      for (int r = 0; r < 16; ++r) acc[r] = fmaf(sB[r][k], wv, acc[r]);
    }
#pragma unroll
    for (int r = 0; r < 16; ++r) sC[r][tid] = gelu_f(acc[r]);
  }
  __syncthreads();
  if (tid < 70) {
    float acc[16];
#pragma unroll
    for (int r = 0; r < 16; ++r) acc[r] = b3[tid];
    for (int k = 0; k < 70; ++k) {
      const float wv = w3[k * 70 + tid];
#pragma unroll
      for (int r = 0; r < 16; ++r) acc[r] = fmaf(sC[r][k], wv, acc[r]);
    }
#pragma unroll
    for (int r = 0; r < 16; ++r) sB[r][tid] = gelu_f(acc[r]);
  }
  __syncthreads();
  if (tid < 16) {
    float m = 0.f;
    for (int d = 0; d < 70; ++d) m += sB[tid][d];
    m *= (1.f / 70.f);
    float v = 0.f;
    for (int d = 0; d < 70; ++d) { const float t = sB[tid][d] - m; v += t * t; }
    const float inv = rsqrtf(v * (1.f / 70.f) + 1e-5f);
    for (int d = 0; d < 70; ++d) sB[tid][d] = (sB[tid][d] - m) * inv * lng[d] + lnb[d];
  }
  __syncthreads();
  {
    float acc[16];
#pragma unroll
    for (int r = 0; r < 16; ++r) acc[r] = b4[tid];
    for (int k = 0; k < 70; ++k) {
      const float wv = w4[k * 128 + tid];
#pragma unroll
      for (int r = 0; r < 16; ++r) acc[r] = fmaf(sB[r][k], wv, acc[r]);
    }
#pragma unroll
    for (int r = 0; r < 16; ++r) {
      const int gr = r0 + r;
      x[(size_t)(gr + gr / 1024 + 1) * DIMC + tid] = acc[r];
    }
  }
}

// ---------------------------------------------------------------------------
// bf16 MFMA GEMM, 64x64 tile (proj / mlp): out = [act](Xb @ Wt^T + bias) [+res]
// ---------------------------------------------------------------------------
template<int ACT, int OBF, int RES>
__global__ __launch_bounds__(256) void mgemm_k(
    const unsigned short* __restrict__ Xb, const unsigned short* __restrict__ Wt,
    const float* __restrict__ bias, const float* __restrict__ res,
    void* __restrict__ outp, int rows, int K, int N)
{
  __shared__ unsigned short sX[64][72];
  __shared__ unsigned short sW[64][72];
  const int tid = threadIdx.x;
  const int w = tid >> 6, lane = tid & 63;
  const int col = lane & 15, quad = lane >> 4;
  const int r0 = blockIdx.x * 64, n0 = blockIdx.y * 64;
  const int lr = tid >> 2, lc = tid & 3;
  const int xrow = min(r0 + lr, rows - 1);
  const unsigned short* xsrc = Xb + (size_t)xrow * K + lc * 8;
  const unsigned short* wsrc = Wt + (size_t)(n0 + lr) * K + lc * 8;

  f32x4 acc[4];
#pragma unroll
  for (int t = 0; t < 4; ++t) acc[t] = (f32x4){0.f, 0.f, 0.f, 0.f};

  for (int k0 = 0; k0 < K; k0 += 64) {
    __syncthreads();
    *(uint4*)&sX[lr][lc * 8]      = *(const uint4*)(xsrc + k0);
    *(uint4*)&sX[lr][lc * 8 + 32] = *(const uint4*)(xsrc + k0 + 32);
    *(uint4*)&sW[lr][lc * 8]      = *(const uint4*)(wsrc + k0);
    *(uint4*)&sW[lr][lc * 8 + 32] = *(const uint4*)(wsrc + k0 + 32);
    __syncthreads();
    const bf16x8 aX0 = *(const bf16x8*)&sX[w * 16 + col][quad * 8];
    const bf16x8 aX1 = *(const bf16x8*)&sX[w * 16 + col][32 + quad * 8];
#pragma unroll
    for (int t = 0; t < 4; ++t) {
      const bf16x8 bW0 = *(const bf16x8*)&sW[t * 16 + col][quad * 8];
      const bf16x8 bW1 = *(const bf16x8*)&sW[t * 16 + col][32 + quad * 8];
      acc[t] = __builtin_amdgcn_mfma_f32_16x16x32_bf16(aX0, bW0, acc[t], 0, 0, 0);
      acc[t] = __builtin_amdgcn_mfma_f32_16x16x32_bf16(aX1, bW1, acc[t], 0, 0, 0);
    }
  }
  const int gr_base = r0 + w * 16 + quad * 4;
#pragma unroll
  for (int t = 0; t < 4; ++t) {
    const int n = n0 + t * 16 + col;
    const float bv = bias ? bias[n] : 0.f;
#pragma unroll
    for (int r = 0; r < 4; ++r) {
      const int gr = gr_base + r;
      if (gr < rows) {
        float v = acc[t][r] + bv;
        if (ACT) v = gelu_f(v);
        if (RES) v += res[(size_t)gr * N + n];
        if (OBF) ((unsigned short*)outp)[(size_t)gr * N + n] = f2bf(v);
        else     ((float*)outp)[(size_t)gr * N + n] = v;
      }
    }
  }
}

// ---------------------------------------------------------------------------
// bf16 MFMA GEMM, 128x128 tile (QKV: N=3072), with fused V-transpose epilogue
// ---------------------------------------------------------------------------
template<int OBF, int VT>
__global__ __launch_bounds__(256) void mgemm128_k(
    const unsigned short* __restrict__ Xb, const unsigned short* __restrict__ Wt,
    const float* __restrict__ bias, void* __restrict__ outp,
    unsigned short* __restrict__ vtp, int rows, int K, int N)
{
  __shared__ unsigned short sX[128][72];
  __shared__ unsigned short sW[128][72];
  const int tid = threadIdx.x;
  const int w = tid >> 6, lane = tid & 63;
  const int col = lane & 15, quad = lane >> 4;
  const int wr = w >> 1, wc = w & 1;
  const int r0 = blockIdx.x * 128, n0 = blockIdx.y * 128;

  f32x4 acc[4][4];
#pragma unroll
  for (int i = 0; i < 4; ++i)
#pragma unroll
    for (int j = 0; j < 4; ++j) acc[i][j] = (f32x4){0.f, 0.f, 0.f, 0.f};

  for (int k0 = 0; k0 < K; k0 += 64) {
    __syncthreads();
#pragma unroll
    for (int l = 0; l < 4; ++l) {
      const int idx = l * 256 + tid;
      const int row = idx >> 3, c = idx & 7;
      const int xrow = min(r0 + row, rows - 1);
      *(uint4*)&sX[row][c * 8] = *(const uint4*)(Xb + (size_t)xrow * K + k0 + c * 8);
      *(uint4*)&sW[row][c * 8] = *(const uint4*)(Wt + (size_t)(n0 + row) * K + k0 + c * 8);
    }
    __syncthreads();
    bf16x8 aX[4][2];
#pragma unroll
    for (int i = 0; i < 4; ++i) {
      aX[i][0] = *(const bf16x8*)&sX[wr * 64 + i * 16 + col][quad * 8];
      aX[i][1] = *(const bf16x8*)&sX[wr * 64 + i * 16 + col][32 + quad * 8];
    }
#pragma unroll
    for (int j = 0; j < 4; ++j) {
      const bf16x8 b0 = *(const bf16x8*)&sW[wc * 64 + j * 16 + col][quad * 8];
      const bf16x8 b1 = *(const bf16x8*)&sW[wc * 64 + j * 16 + col][32 + quad * 8];
#pragma unroll
      for (int i = 0; i < 4; ++i) {
        acc[i][j] = __builtin_amdgcn_mfma_f32_16x16x32_bf16(aX[i][0], b0, acc[i][j], 0, 0, 0);
        acc[i][j] = __builtin_amdgcn_mfma_f32_16x16x32_bf16(aX[i][1], b1, acc[i][j], 0, 0, 0);
      }
    }
  }
  const bool dovt = VT && (n0 >= 2048);
#pragma unroll
  for (int i = 0; i < 4; ++i) {
    const int gr_base = r0 + wr * 64 + i * 16 + quad * 4;
    int bb[4], mm[4];
    if (dovt) {
#pragma unroll
      for (int r = 0; r < 4; ++r) {
        const int gr = gr_base + r;
        bb[r] = gr / 1025;
        mm[r] = gr - bb[r] * 1025;
      }
    }
#pragma unroll
    for (int j = 0; j < 4; ++j) {
      const int n = n0 + wc * 64 + j * 16 + col;
      const float bv = bias ? bias[n] : 0.f;
      const int hh = (n - 2048) >> 7;
      const int d  = (n - 2048) & 127;
#pragma unroll
      for (int r = 0; r < 4; ++r) {
        const int gr = gr_base + r;
        if (gr < rows) {
          const float v = acc[i][j][r] + bv;
          const unsigned short bf = f2bf(v);
          if (OBF) ((unsigned short*)outp)[(size_t)gr * N + n] = bf;
          else     ((float*)outp)[(size_t)gr * N + n] = v;
          if (dovt) vtp[(((size_t)(bb[r] * NHEADS + hh) * DIMC + d) * ACS) + mm[r]] = bf;
        }
      }
    }
  }
}

// ---------------------------------------------------------------------------
// Wave-per-row LayerNorm; optional bf16 shadow out; optional fused gamma
// ---------------------------------------------------------------------------
__global__ __launch_bounds__(256) void ln_rows_k(
    const float* __restrict__ in, float* __restrict__ out,
    unsigned short* __restrict__ outb,
    const float* __restrict__ g, const float* __restrict__ b,
    const float* __restrict__ gw, const float* __restrict__ gb,
    float* __restrict__ gamout, int rows, int D)
{
  const int wv = (blockIdx.x * blockDim.x + threadIdx.x) >> 6;
  const int lane = threadIdx.x & 63;
  if (wv >= rows) return;
  const float* r = in + (size_t)wv * D;
  float s = 0.f;
  for (int d = lane; d < D; d += 64) s += r[d];
  for (int off = 32; off; off >>= 1) s += __shfl_down(s, off);
  const float mean = __shfl(s, 0) / (float)D;
  float v = 0.f;
  for (int d = lane; d < D; d += 64) { float t = r[d] - mean; v += t * t; }
  for (int off = 32; off; off >>= 1) v += __shfl_down(v, off);
  const float inv = rsqrtf(__shfl(v, 0) / (float)D + 1e-5f);
  float* orow = out + (size_t)wv * D;
  float a0 = 0.f, a1 = 0.f;
  for (int d = lane; d < D; d += 64) {
    const float o = (r[d] - mean) * inv * g[d] + b[d];
    orow[d] = o;
    if (outb) outb[(size_t)wv * D + d] = f2bf(o);
    if (gw) { a0 = fmaf(o, gw[2 * d], a0); a1 = fmaf(o, gw[2 * d + 1], a1); }
  }
  if (gw) {
    for (int off = 32; off; off >>= 1) { a0 += __shfl_down(a0, off); a1 += __shfl_down(a1, off); }
    if (lane == 0) {
      gamout[(size_t)wv * 2 + 0] = expf(a0 + gb[0]);
      gamout[(size_t)wv * 2 + 1] = expf(a1 + gb[1]);
    }
  }
}

// ---------------------------------------------------------------------------
// prep: bit-packed adj_cls
// ---------------------------------------------------------------------------
__global__ __launch_bounds__(256) void adjp_k(const float* __restrict__ adj,
                                              unsigned long long* __restrict__ adjp)
{
  const int n = blockIdx.x;
  const int b = blockIdx.y;
  const int wv = threadIdx.x >> 6, lane = threadIdx.x & 63;
  for (int w = wv; w < 17; w += 4) {
    const int m = w * 64 + lane;
    float av = 0.f;
    if (n == 0) av = (m == 0) ? 1.f : 0.f;
    else if (m >= 1 && m <= NSEQ) av = adj[((size_t)b * NSEQ + (n - 1)) * NSEQ + (m - 1)];
    const unsigned long long mask = __ballot(av != 0.f);
    if (lane == 0) adjp[((size_t)b * M_ + n) * 17 + w] = mask;
  }
}

// ---------------------------------------------------------------------------
// prep: Wt[n][k] = bf16(W[k][n])
// ---------------------------------------------------------------------------
__global__ void wtrans_k(const float* __restrict__ W, unsigned short* __restrict__ Wt,
                         int K, int N)
{
  __shared__ float t[32][33];
  const int k0 = blockIdx.x * 32, n0 = blockIdx.y * 32;
  const float* Wd = W + (size_t)blockIdx.z * K * N;
  unsigned short* Wtd = Wt + (size_t)blockIdx.z * K * N;
  for (int i = threadIdx.y; i < 32; i += 8)
    t[i][threadIdx.x] = Wd[(size_t)(k0 + i) * N + n0 + threadIdx.x];
  __syncthreads();
  for (int i = threadIdx.y; i < 32; i += 8)
    Wtd[(size_t)(n0 + i) * K + k0 + threadIdx.x] = f2bf(t[threadIdx.x][i]);
}

// ---------------------------------------------------------------------------
// bf16 MFMA flash attention (R11/R12 core) + REGISTER PREFETCH of the next
// tile's K/Vt staging loads: the global->LDS path was load -> vmcnt(0) ->
// ds_write -> barrier with ~300cy L2 latency exposed 17x; now the loads for
// tile kt+1 issue right after the staging barrier and overlap tile kt's
// QK/softmax/PV compute. +32 VGPR (8x uint4) -> ~132 total; at 132 VGPR the
// wave budget still allows 3 waves/SIMD, and LDS (45KB -> 3 blocks/CU)
// remains the binding occupancy cap, so no R5-style cliff.
// ---------------------------------------------------------------------------
__global__ __launch_bounds__(256) void attn_mfma_k(
    const unsigned short* __restrict__ qkv, const float* __restrict__ gamma,
    const unsigned long long* __restrict__ adjp, const unsigned short* __restrict__ vt,
    unsigned short* __restrict__ o)
{
  __shared__ unsigned short sK[64][136];
  __shared__ unsigned short sVt[128][72];
  __shared__ unsigned short sP[64][72];

  const int hh = blockIdx.x, qt = blockIdx.y, b = blockIdx.z;
  const int tid = threadIdx.x;
  const int w = tid >> 6;
  const int lane = tid & 63;
  const int col = lane & 15;
  const int quad = lane >> 4;
  const int n0 = qt * 64;
  const int qbase = n0 + w * 16;
  const float scale = 0.088388347648318447f;

  bf16x8 aQ[4];
  {
    const int qrow = min(qbase + col, 1024);
    const unsigned short* qp = qkv + ((size_t)(b * M_ + qrow)) * QKV3 + hh * DIMC + quad * 8;
#pragma unroll
    for (int c = 0; c < 4; ++c) aQ[c] = *(const bf16x8*)(qp + c * 32);
  }
  float g0[4], g1[4];
  size_t adjo[4];
#pragma unroll
  for (int r = 0; r < 4; ++r) {
    const int nc = min(qbase + quad * 4 + r, 1024);
    g0[r] = gamma[(size_t)(b * M_ + nc) * 2 + 0] * scale;
    g1[r] = gamma[(size_t)(b * M_ + nc) * 2 + 1];
    adjo[r] = ((size_t)b * M_ + nc) * 17;
  }

  float l_i[4] = {0.f, 0.f, 0.f, 0.f};
  f32x4 Oacc[8];
#pragma unroll
  for (int t = 0; t < 8; ++t) Oacc[t] = (f32x4){0.f, 0.f, 0.f, 0.f};

  const size_t vtbase = ((size_t)(b * NHEADS + hh)) * DIMC * ACS;

  // per-l fixed address components
  const int kM = tid >> 4, kC = tid & 15;          // K: row kM+16l, chunk kC
  const int vD = tid >> 3, vMC = tid & 7;          // Vt: d = vD+32l, mchunk vMC
  const unsigned short* kbase = qkv + (size_t)(b * M_) * QKV3 + 1024 + hh * DIMC + kC * 8;
  const unsigned short* vbase = vt + vtbase + vMC * 8;

  uint4 pK[4], pV[4];
  // prefetch tile 0
#pragma unroll
  for (int l = 0; l < 4; ++l) {
    const int gm = kM + l * 16;
    pK[l] = (gm < M_) ? *(const uint4*)(kbase + (size_t)gm * QKV3) : make_uint4(0u, 0u, 0u, 0u);
    pV[l] = *(const uint4*)(vbase + (size_t)(vD + l * 32) * ACS);
  }

  for (int kt = 0; kt < 17; ++kt) {
    const int m0 = kt * 64;
    __syncthreads();
    // write prefetched tile into LDS
#pragma unroll
    for (int l = 0; l < 4; ++l) {
      *(uint4*)&sK[kM + l * 16][kC * 8] = pK[l];
      const int d = vD + l * 32;
      const int swc = vMC ^ ((d >> 3) & 7);
      *(uint4*)&sVt[d][swc * 8] = pV[l];
    }
    __syncthreads();
    // issue next tile's loads — overlap with compute below
    if (kt < 16) {
      const int m0n = m0 + 64;
#pragma unroll
      for (int l = 0; l < 4; ++l) {
        const int gm = m0n + kM + l * 16;
        pK[l] = (gm < M_) ? *(const uint4*)(kbase + (size_t)gm * QKV3) : make_uint4(0u, 0u, 0u, 0u);
        pV[l] = *(const uint4*)(vbase + (size_t)(vD + l * 32) * ACS + m0n);
      }
    }

    unsigned long long mk[4];
#pragma unroll
    for (int r = 0; r < 4; ++r) mk[r] = adjp[adjo[r] + kt];

    f32x4 Sacc[4];
#pragma unroll
    for (int t = 0; t < 4; ++t) Sacc[t] = (f32x4){0.f, 0.f, 0.f, 0.f};
#pragma unroll
    for (int t = 0; t < 4; ++t) {
#pragma unroll
      for (int c = 0; c < 4; ++c) {
        const bf16x8 bK = *(const bf16x8*)&sK[t * 16 + col][c * 32 + quad * 8];
        Sacc[t] = __builtin_amdgcn_mfma_f32_16x16x32_bf16(aQ[c], bK, Sacc[t], 0, 0, 0);
      }
    }

#pragma unroll
    for (int t = 0; t < 4; ++t) {
      const int m = m0 + t * 16 + col;
      const bool mv = (m < M_);
      const int chb = t * 2 + (col >> 3);
      const int sh = t * 16 + col;
#pragma unroll
      for (int r = 0; r < 4; ++r) {
        const float bias = ((mk[r] >> sh) & 1ull) ? g1[r] : 0.f;
        const float s = fmaf(g0[r], Sacc[t][r], bias);
        const float pv = mv ? __expf(s) : 0.f;
        l_i[r] += pv;
        const int ql = w * 16 + quad * 4 + r;
        sP[ql][((chb ^ (ql & 7)) * 8) + (col & 7)] = f2bf(pv);
      }
    }

#pragma unroll
    for (int ch = 0; ch < 2; ++ch) {
      const int r0a = w * 16 + col;
      const bf16x8 aP = *(const bf16x8*)&sP[r0a][(((ch * 4 + quad) ^ (col & 7)) * 8)];
#pragma unroll
      for (int t = 0; t < 8; ++t) {
        const int pc = (ch * 4 + quad) ^ ((t * 2 + (col >> 3)) & 7);
        const bf16x8 bV = *(const bf16x8*)&sVt[t * 16 + col][pc * 8];
        Oacc[t] = __builtin_amdgcn_mfma_f32_16x16x32_bf16(aP, bV, Oacc[t], 0, 0, 0);
      }
    }
  }

#pragma unroll
  for (int r = 0; r < 4; ++r) {
    float s = l_i[r];
    s += __shfl_xor(s, 1);
    s += __shfl_xor(s, 2);
    s += __shfl_xor(s, 4);
    s += __shfl_xor(s, 8);
    const int n = qbase + quad * 4 + r;
    if (n < M_) {
      const float invl = 1.f / s;
      unsigned short* orow = o + ((size_t)(b * M_ + n)) * (NHEADS * DIMC) + hh * DIMC + col;
#pragma unroll
      for (int t = 0; t < 8; ++t) orow[t * 16] = f2bf(Oacc[t][r] * invl);
    }
  }
}

// ---------------------------------------------------------------------------
// Fused head (R12)
// ---------------------------------------------------------------------------
__global__ __launch_bounds__(256) void head_fused_k(
    const float* __restrict__ x,
    const float* __restrict__ hlg, const float* __restrict__ hlb,
    const float* __restrict__ hw, const float* __restrict__ hb,
    const float* __restrict__ pw1, const float* __restrict__ pb1,
    const float* __restrict__ pw2, const float* __restrict__ pb2,
    const float* __restrict__ pw3, const float* __restrict__ pb3,
    const float* __restrict__ plg, const float* __restrict__ plb,
    const float* __restrict__ pw4, const float* __restrict__ pb4,
    float* __restrict__ out_c, float* __restrict__ out_p)
{
  __shared__ float sA[8][128];
  __shared__ float sB[8][128];
  const int tid = threadIdx.x;

  for (int i = tid; i < 8 * 128; i += 256) {
    const int bb = i >> 7, d = i & 127;
    sA[bb][d] = x[(size_t)bb * M_ * DIMC + d];
  }
  __syncthreads();
  if (tid < 8) {
    float m = 0.f;
    for (int d = 0; d < 128; ++d) m += sA[tid][d];
    m *= (1.f / 128.f);
    float v = 0.f;
    for (int d = 0; d < 128; ++d) { const float t = sA[tid][d] - m; v += t * t; }
    const float inv = rsqrtf(v * (1.f / 128.f) + 1e-5f);
    for (int d = 0; d < 128; ++d) sA[tid][d] = (sA[tid][d] - m) * inv * hlg[d] + hlb[d];
  }
  __syncthreads();
  {
    const int j = tid & 127, rb = (tid >> 7) * 4;
    float acc[4];
#pragma unroll
    for (int r = 0; r < 4; ++r) acc[r] = hb[j];
    for (int k = 0; k < 128; ++k) {
      const float wv = hw[k * 128 + j];
#pragma unroll
      for (int r = 0; r < 4; ++r) acc[r] = fmaf(sA[rb + r][k], wv, acc[r]);
    }
#pragma unroll
    for (int r = 0; r < 4; ++r) { sB[rb + r][j] = acc[r]; out_c[(rb + r) * 128 + j] = acc[r]; }
  }
  __syncthreads();
  const float* Ws[3] = {pw1, pw2, pw3};
  const float* Bs[3] = {pb1, pb2, pb3};
  for (int s = 0; s < 3; ++s) {
    const float (*src)[128] = (s & 1) ? sA : sB;
    float (*dst)[128] = (s & 1) ? sB : sA;
    const int j = tid & 127, rb = (tid >> 7) * 4;
    float acc[4];
#pragma unroll
    for (int r = 0; r < 4; ++r) acc[r] = Bs[s][j];
    for (int k = 0; k < 128; ++k) {
      const float wv = Ws[s][k * 128 + j];
#pragma unroll
      for (int r = 0; r < 4; ++r) acc[r] = fmaf(src[rb + r][k], wv, acc[r]);
    }
#pragma unroll
    for (int r = 0; r < 4; ++r) dst[rb + r][j] = gelu_f(acc[r]);
    __syncthreads();
  }
  if (tid < 8) {
    float m = 0.f;
    for (int d = 0; d < 128; ++d) m += sA[tid][d];
    m *= (1.f / 128.f);
    float v = 0.f;
    for (int d = 0; d < 128; ++d) { const float t = sA[tid][d] - m; v += t * t; }
    const float inv = rsqrtf(v * (1.f / 128.f) + 1e-5f);
    for (int d = 0; d < 128; ++d) sA[tid][d] = (sA[tid][d] - m) * inv * plg[d] + plb[d];
  }
  __syncthreads();
  for (int j = tid; j < 1000; j += 256) {
    float acc[8];
#pragma unroll
    for (int bb = 0; bb < 8; ++bb) acc[bb] = pb4[j];
    for (int k = 0; k < 128; ++k) {
      const float wv = pw4[(size_t)k * 1000 + j];
#pragma unroll
      for (int bb = 0; bb < 8; ++bb) acc[bb] = fmaf(sA[bb][k], wv, acc[bb]);
    }
#pragma unroll
    for (int bb = 0; bb < 8; ++bb) out_p[bb * 1000 + j] = acc[bb];
  }
}

// ---------------------------------------------------------------------------
__global__ void fill_cls_k(const float* __restrict__ cls, float* __restrict__ x)
{
  x[(size_t)blockIdx.x * M_ * DIMC + threadIdx.x] = cls[threadIdx.x];
}

// ---------------------------------------------------------------------------
extern "C" void kernel_launch(void* const* d_in, const int* in_sizes, int n_in,
                              void* d_out, int out_size, void* d_ws, size_t ws_size,
                              hipStream_t stream)
{
  (void)in_sizes; (void)n_in; (void)out_size; (void)ws_size;
  const float* node_feat = (const float*)d_in[0];
  const float* adj       = (const float*)d_in[1];
  const float* lapl      = (const float*)d_in[2];
  const float* cls_token = (const float*)d_in[3];
  const float* pe_w1 = (const float*)d_in[4];
  const float* pe_b1 = (const float*)d_in[5];
  const float* pe_w2 = (const float*)d_in[6];
  const float* pe_b2 = (const float*)d_in[7];
  const float* pe_w3 = (const float*)d_in[8];
  const float* pe_b3 = (const float*)d_in[9];
  const float* pe_lng = (const float*)d_in[10];
  const float* pe_lnb = (const float*)d_in[11];
  const float* pe_w4 = (const float*)d_in[12];
  const float* pe_b4 = (const float*)d_in[13];
  const float* blk_ln1_g = (const float*)d_in[14];
  const float* blk_ln1_b = (const float*)d_in[15];
  const float* blk_qkv_w = (const float*)d_in[16];
  const float* blk_proj_w = (const float*)d_in[17];
  const float* blk_proj_b = (const float*)d_in[18];
  const float* blk_gamma_w = (const float*)d_in[19];
  const float* blk_gamma_b = (const float*)d_in[20];
  const float* blk_ln2_g = (const float*)d_in[21];
  const float* blk_ln2_b = (const float*)d_in[22];
  const float* blk_mlp_w1 = (const float*)d_in[23];
  const float* blk_mlp_b1 = (const float*)d_in[24];
  const float* blk_mlp_w2 = (const float*)d_in[25];
  const float* blk_mlp_b2 = (const float*)d_in[26];
  const float* head_lng = (const float*)d_in[27];
  const float* head_lnb = (const float*)d_in[28];
  const float* head_w = (const float*)d_in[29];
  const float* head_b = (const float*)d_in[30];
  const float* proj_w1 = (const float*)d_in[31];
  const float* proj_b1 = (const float*)d_in[32];
  const float* proj_w2 = (const float*)d_in[33];
  const float* proj_b2 = (const float*)d_in[34];
  const float* proj_w3 = (const float*)d_in[35];
  const float* proj_b3 = (const float*)d_in[36];
  const float* proj_lng = (const float*)d_in[37];
  const float* proj_lnb = (const float*)d_in[38];
  const float* proj_w4 = (const float*)d_in[39];
  const float* proj_b4 = (const float*)d_in[40];

  // ---- workspace layout ----
  float* ws   = (float*)d_ws;
  float* x    = ws;                        // 1,049,600 f
  float* h    = x + 1049600;               // 1,049,600 f
  float* gam  = h + 1049600;               // 16,400 f
  float* obuf = gam + 16400;               // 5,248,000 f region
  unsigned short* obufb = (unsigned short*)obuf;             // 8200*1024 bf16
  unsigned short* hidb  = (unsigned short*)(obuf + 4198400); // 8200*256 bf16
  float* sm  = obuf + 5248000;             // 8,192 f
  unsigned short* hb   = (unsigned short*)(sm + 8192);       // 8200*128 bf16
  unsigned short* qkv  = hb + 1049600;     // 25,190,400 us
  unsigned long long* adjp = (unsigned long long*)(qkv + 25190400);  // 139,400 u64
  unsigned short* vt   = (unsigned short*)(adjp + 139400 + 88);      // 8,912,896 us
  unsigned short* qkvWt = vt + 8912896;    // 5*393216
  unsigned short* projWt = qkvWt + 5 * 393216;
  unsigned short* mlp1Wt = projWt + 5 * 131072;
  unsigned short* mlp2Wt = mlp1Wt + 5 * 32768;

  float* out_c = (float*)d_out;            // (8,128)
  float* out_p = out_c + NB * DIMC;        // (8,1000)

  // ---- prep ----
  adjp_k<<<dim3(M_, NB), 256, 0, stream>>>(adj, adjp);
  wtrans_k<<<dim3(4, 96, 5), dim3(32, 8), 0, stream>>>(blk_qkv_w, qkvWt, 128, 3072);
  wtrans_k<<<dim3(32, 4, 5), dim3(32, 8), 0, stream>>>(blk_proj_w, projWt, 1024, 128);
  wtrans_k<<<dim3(4, 8, 5), dim3(32, 8), 0, stream>>>(blk_mlp_w1, mlp1Wt, 128, 256);
  wtrans_k<<<dim3(8, 4, 5), dim3(32, 8), 0, stream>>>(blk_mlp_w2, mlp2Wt, 256, 128);

  // ---- PE encoder ----
  pe_fused_k<<<512, 128, 0, stream>>>(node_feat, lapl, pe_w1, pe_b1, pe_w2, pe_b2,
                                      pe_w3, pe_b3, pe_lng, pe_lnb, pe_w4, pe_b4, x);
  fill_cls_k<<<NB, DIMC, 0, stream>>>(cls_token, x);

  // ---- transformer layers ----
  const int lnGrid = (ROWS * 64 + 255) / 256;  // 2050
  for (int i = 0; i < 5; ++i) {
    const float* ln1g = blk_ln1_g + i * DIMC;
    const float* ln1b = blk_ln1_b + i * DIMC;
    const float* pb   = blk_proj_b + i * DIMC;
    const float* gw   = blk_gamma_w + (size_t)i * DIMC * 2;
    const float* gb   = blk_gamma_b + i * 2;
    const float* ln2g = blk_ln2_g + i * DIMC;
    const float* ln2b = blk_ln2_b + i * DIMC;
    const float* mb1  = blk_mlp_b1 + i * 256;
    const float* mb2  = blk_mlp_b2 + i * DIMC;
    const unsigned short* qw = qkvWt + (size_t)i * 393216;
    const unsigned short* pw = projWt + (size_t)i * 131072;
    const unsigned short* m1w = mlp1Wt + (size_t)i * 32768;
    const unsigned short* m2w = mlp2Wt + (size_t)i * 32768;

    ln_rows_k<<<lnGrid, 256, 0, stream>>>(x, h, hb, ln1g, ln1b, gw, gb, gam, ROWS, DIMC);
    mgemm128_k<1, 1><<<dim3(65, 24), 256, 0, stream>>>(hb, qw, nullptr, qkv, vt, ROWS, 128, 3072);
    attn_mfma_k<<<dim3(NHEADS, 17, NB), 256, 0, stream>>>(qkv, gam, adjp, vt, obufb);
    mgemm_k<0, 0, 1><<<dim3(129, 2), 256, 0, stream>>>(obufb, pw, pb, h, x, ROWS, 1024, 128);
    ln_rows_k<<<lnGrid, 256, 0, stream>>>(x, h, hb, ln2g, ln2b, nullptr, nullptr, nullptr, ROWS, DIMC);
    mgemm_k<1, 1, 0><<<dim3(129, 4), 256, 0, stream>>>(hb, m1w, mb1, nullptr, hidb, ROWS, 128, 256);
    mgemm_k<0, 0, 1><<<dim3(129, 2), 256, 0, stream>>>(hidb, m2w, mb2, h, x, ROWS, 256, 128);
  }

  // ---- fused head ----
  head_fused_k<<<1, 256, 0, stream>>>(x, head_lng, head_lnb, head_w, head_b,
                                      proj_w1, proj_b1, proj_w2, proj_b2,
                                      proj_w3, proj_b3, proj_lng, proj_lnb,
                                      proj_w4, proj_b4, out_c, out_p);
}

// Round 15
// 1602.236 us; speedup vs baseline: 1.1028x; 1.1028x over previous
//
#include <hip/hip_runtime.h>
#include <hip/hip_bf16.h>
#include <math.h>

// Problem constants
#define NB 8
#define NSEQ 1024
#define M_ 1025                 // NSEQ + 1 (cls)
#define ROWS (NB * M_)          // 8200
#define DIMC 128
#define NHEADS 8
#define QKV3 3072               // 3*8*128
#define PEROWS (NB * NSEQ)      // 8192
#define ACS 1088                // vt padded column stride

typedef __attribute__((ext_vector_type(8))) short bf16x8;
typedef __attribute__((ext_vector_type(4))) float f32x4;

__device__ __forceinline__ float gelu_f(float x) {
  return 0.5f * x * (1.f + erff(x * 0.70710678118654752440f));
}

__device__ __forceinline__ unsigned short f2bf(float f) {
  __hip_bfloat16 h = __float2bfloat16(f);
  return *reinterpret_cast<unsigned short*>(&h);
}

__device__ __forceinline__ float bf2f(unsigned short u) {
  union { unsigned int i; float f; } c;
  c.i = ((unsigned int)u) << 16;
  return c.f;
}

// ---------------------------------------------------------------------------
// Fused PE encoder: concat(3+32) -> gelu GEMM 35->70 -> gelu 70->70 ->
// gelu 70->70 -> LN(70) -> GEMM 70->128 -> x (remapped rows, skipping cls).
// ---------------------------------------------------------------------------
__global__ __launch_bounds__(128) void pe_fused_k(
    const float* __restrict__ nf, const float* __restrict__ lp,
    const float* __restrict__ w1, const float* __restrict__ b1,
    const float* __restrict__ w2, const float* __restrict__ b2,
    const float* __restrict__ w3, const float* __restrict__ b3,
    const float* __restrict__ lng, const float* __restrict__ lnb,
    const float* __restrict__ w4, const float* __restrict__ b4,
    float* __restrict__ x)
{
  __shared__ float sA[16][36];
  __shared__ float sB[16][72];
  __shared__ float sC[16][72];
  const int tid = threadIdx.x;
  const int r0 = blockIdx.x * 16;

  for (int i = tid; i < 16 * 35; i += 128) {
    const int r = i / 35, c = i - r * 35;
    const int gr = r0 + r;
    sA[r][c] = (c < 3) ? nf[(size_t)gr * 3 + c] : lp[(size_t)gr * 32 + (c - 3)];
  }
  __syncthreads();
  if (tid < 70) {
    float acc[16];
#pragma unroll
    for (int r = 0; r < 16; ++r) acc[r] = b1[tid];
    for (int k = 0; k < 35; ++k) {
      const float wv = w1[k * 70 + tid];
#pragma unroll
      for (int r = 0; r < 16; ++r) acc[r] = fmaf(sA[r][k], wv, acc[r]);
    }
#pragma unroll
    for (int r = 0; r < 16; ++r) sB[r][tid] = gelu_f(acc[r]);
  }
  __syncthreads();
  if (tid < 70) {
    float acc[16];
#pragma unroll
    for (int r = 0; r < 16; ++r) acc[r] = b2[tid];
    for (int k = 0; k < 70; ++k) {
      const float wv = w2[k * 70 + tid];
#pragma unroll
      for (int r = 0; r < 16; ++r) acc[r] = fmaf(sB[r][k], wv, acc[r]);
    }
#pragma unroll
    for (int r = 0; r < 16; ++r) sC[r][tid] = gelu_f(acc[r]);
  }
  __syncthreads();
  if (tid < 70) {
    float acc[16];
#pragma unroll
    for (int r = 0; r < 16; ++r) acc[r] = b3[tid];
    for (int k = 0; k < 70; ++k) {
      const float wv = w3[k * 70 + tid];
#pragma unroll
      for (int r = 0; r < 16; ++r) acc[r] = fmaf(sC[r][k], wv, acc[r]);
    }
#pragma unroll
    for (int r = 0; r < 16; ++r) sB[r][tid] = gelu_f(acc[r]);
  }
  __syncthreads();
  if (tid < 16) {
    float m = 0.f;
    for (int d = 0; d < 70; ++d) m += sB[tid][d];
    m *= (1.f / 70.f);
    float v = 0.f;
    for (int d = 0; d < 70; ++d) { const float t = sB[tid][d] - m; v += t * t; }
    const float inv = rsqrtf(v * (1.f / 70.f) + 1e-5f);
    for (int d = 0; d < 70; ++d) sB[tid][d] = (sB[tid][d] - m) * inv * lng[d] + lnb[d];
  }
  __syncthreads();
  {
    float acc[16];
#pragma unroll
    for (int r = 0; r < 16; ++r) acc[r] = b4[tid];
    for (int k = 0; k < 70; ++k) {
      const float wv = w4[k * 128 + tid];
#pragma unroll
      for (int r = 0; r < 16; ++r) acc[r] = fmaf(sB[r][k], wv, acc[r]);
    }
#pragma unroll
    for (int r = 0; r < 16; ++r) {
      const int gr = r0 + r;
      x[(size_t)(gr + gr / 1024 + 1) * DIMC + tid] = acc[r];
    }
  }
}

// ---------------------------------------------------------------------------
// bf16 MFMA GEMM, 64x64 tile (proj / mlp): out = [act](Xb @ Wt^T + bias) [+res]
// ---------------------------------------------------------------------------
template<int ACT, int OBF, int RES>
__global__ __launch_bounds__(256) void mgemm_k(
    const unsigned short* __restrict__ Xb, const unsigned short* __restrict__ Wt,
    const float* __restrict__ bias, const float* __restrict__ res,
    void* __restrict__ outp, int rows, int K, int N)
{
  __shared__ unsigned short sX[64][72];
  __shared__ unsigned short sW[64][72];
  const int tid = threadIdx.x;
  const int w = tid >> 6, lane = tid & 63;
  const int col = lane & 15, quad = lane >> 4;
  const int r0 = blockIdx.x * 64, n0 = blockIdx.y * 64;
  const int lr = tid >> 2, lc = tid & 3;
  const int xrow = min(r0 + lr, rows - 1);
  const unsigned short* xsrc = Xb + (size_t)xrow * K + lc * 8;
  const unsigned short* wsrc = Wt + (size_t)(n0 + lr) * K + lc * 8;

  f32x4 acc[4];
#pragma unroll
  for (int t = 0; t < 4; ++t) acc[t] = (f32x4){0.f, 0.f, 0.f, 0.f};

  for (int k0 = 0; k0 < K; k0 += 64) {
    __syncthreads();
    *(uint4*)&sX[lr][lc * 8]      = *(const uint4*)(xsrc + k0);
    *(uint4*)&sX[lr][lc * 8 + 32] = *(const uint4*)(xsrc + k0 + 32);
    *(uint4*)&sW[lr][lc * 8]      = *(const uint4*)(wsrc + k0);
    *(uint4*)&sW[lr][lc * 8 + 32] = *(const uint4*)(wsrc + k0 + 32);
    __syncthreads();
    const bf16x8 aX0 = *(const bf16x8*)&sX[w * 16 + col][quad * 8];
    const bf16x8 aX1 = *(const bf16x8*)&sX[w * 16 + col][32 + quad * 8];
#pragma unroll
    for (int t = 0; t < 4; ++t) {
      const bf16x8 bW0 = *(const bf16x8*)&sW[t * 16 + col][quad * 8];
      const bf16x8 bW1 = *(const bf16x8*)&sW[t * 16 + col][32 + quad * 8];
      acc[t] = __builtin_amdgcn_mfma_f32_16x16x32_bf16(aX0, bW0, acc[t], 0, 0, 0);
      acc[t] = __builtin_amdgcn_mfma_f32_16x16x32_bf16(aX1, bW1, acc[t], 0, 0, 0);
    }
  }
  const int gr_base = r0 + w * 16 + quad * 4;
#pragma unroll
  for (int t = 0; t < 4; ++t) {
    const int n = n0 + t * 16 + col;
    const float bv = bias ? bias[n] : 0.f;
#pragma unroll
    for (int r = 0; r < 4; ++r) {
      const int gr = gr_base + r;
      if (gr < rows) {
        float v = acc[t][r] + bv;
        if (ACT) v = gelu_f(v);
        if (RES) v += res[(size_t)gr * N + n];
        if (OBF) ((unsigned short*)outp)[(size_t)gr * N + n] = f2bf(v);
        else     ((float*)outp)[(size_t)gr * N + n] = v;
      }
    }
  }
}

// ---------------------------------------------------------------------------
// bf16 MFMA GEMM, 128x128 tile (QKV: N=3072). 4 waves 2x2, 64x64 out/wave.
// VT=1: blocks with n0>=2048 (the V output region) additionally scatter
// bf16 V values into vt[b][h][d][m] — fuses the V global transpose.
// (vt m-pad 1025..1087 stays garbage; attention masks it with P=0 and the
// 0xAA ws poison is a finite bf16, so garbage*0 == 0.)
// ---------------------------------------------------------------------------
template<int OBF, int VT>
__global__ __launch_bounds__(256) void mgemm128_k(
    const unsigned short* __restrict__ Xb, const unsigned short* __restrict__ Wt,
    const float* __restrict__ bias, void* __restrict__ outp,
    unsigned short* __restrict__ vtp, int rows, int K, int N)
{
  __shared__ unsigned short sX[128][72];
  __shared__ unsigned short sW[128][72];
  const int tid = threadIdx.x;
  const int w = tid >> 6, lane = tid & 63;
  const int col = lane & 15, quad = lane >> 4;
  const int wr = w >> 1, wc = w & 1;
  const int r0 = blockIdx.x * 128, n0 = blockIdx.y * 128;

  f32x4 acc[4][4];
#pragma unroll
  for (int i = 0; i < 4; ++i)
#pragma unroll
    for (int j = 0; j < 4; ++j) acc[i][j] = (f32x4){0.f, 0.f, 0.f, 0.f};

  for (int k0 = 0; k0 < K; k0 += 64) {
    __syncthreads();
#pragma unroll
    for (int l = 0; l < 4; ++l) {
      const int idx = l * 256 + tid;
      const int row = idx >> 3, c = idx & 7;
      const int xrow = min(r0 + row, rows - 1);
      *(uint4*)&sX[row][c * 8] = *(const uint4*)(Xb + (size_t)xrow * K + k0 + c * 8);
      *(uint4*)&sW[row][c * 8] = *(const uint4*)(Wt + (size_t)(n0 + row) * K + k0 + c * 8);
    }
    __syncthreads();
    bf16x8 aX[4][2];
#pragma unroll
    for (int i = 0; i < 4; ++i) {
      aX[i][0] = *(const bf16x8*)&sX[wr * 64 + i * 16 + col][quad * 8];
      aX[i][1] = *(const bf16x8*)&sX[wr * 64 + i * 16 + col][32 + quad * 8];
    }
#pragma unroll
    for (int j = 0; j < 4; ++j) {
      const bf16x8 b0 = *(const bf16x8*)&sW[wc * 64 + j * 16 + col][quad * 8];
      const bf16x8 b1 = *(const bf16x8*)&sW[wc * 64 + j * 16 + col][32 + quad * 8];
#pragma unroll
      for (int i = 0; i < 4; ++i) {
        acc[i][j] = __builtin_amdgcn_mfma_f32_16x16x32_bf16(aX[i][0], b0, acc[i][j], 0, 0, 0);
        acc[i][j] = __builtin_amdgcn_mfma_f32_16x16x32_bf16(aX[i][1], b1, acc[i][j], 0, 0, 0);
      }
    }
  }
  const bool dovt = VT && (n0 >= 2048);
#pragma unroll
  for (int i = 0; i < 4; ++i) {
    const int gr_base = r0 + wr * 64 + i * 16 + quad * 4;
    int bb[4], mm[4];
    if (dovt) {
#pragma unroll
      for (int r = 0; r < 4; ++r) {
        const int gr = gr_base + r;
        bb[r] = gr / 1025;
        mm[r] = gr - bb[r] * 1025;
      }
    }
#pragma unroll
    for (int j = 0; j < 4; ++j) {
      const int n = n0 + wc * 64 + j * 16 + col;
      const float bv = bias ? bias[n] : 0.f;
      const int hh = (n - 2048) >> 7;
      const int d  = (n - 2048) & 127;
#pragma unroll
      for (int r = 0; r < 4; ++r) {
        const int gr = gr_base + r;
        if (gr < rows) {
          const float v = acc[i][j][r] + bv;
          const unsigned short bf = f2bf(v);
          if (OBF) ((unsigned short*)outp)[(size_t)gr * N + n] = bf;
          else     ((float*)outp)[(size_t)gr * N + n] = v;
          if (dovt) vtp[(((size_t)(bb[r] * NHEADS + hh) * DIMC + d) * ACS) + mm[r]] = bf;
        }
      }
    }
  }
}

// ---------------------------------------------------------------------------
// Wave-per-row LayerNorm; optional bf16 shadow out; optional fused gamma
// ---------------------------------------------------------------------------
__global__ __launch_bounds__(256) void ln_rows_k(
    const float* __restrict__ in, float* __restrict__ out,
    unsigned short* __restrict__ outb,
    const float* __restrict__ g, const float* __restrict__ b,
    const float* __restrict__ gw, const float* __restrict__ gb,
    float* __restrict__ gamout, int rows, int D)
{
  const int wv = (blockIdx.x * blockDim.x + threadIdx.x) >> 6;
  const int lane = threadIdx.x & 63;
  if (wv >= rows) return;
  const float* r = in + (size_t)wv * D;
  float s = 0.f;
  for (int d = lane; d < D; d += 64) s += r[d];
  for (int off = 32; off; off >>= 1) s += __shfl_down(s, off);
  const float mean = __shfl(s, 0) / (float)D;
  float v = 0.f;
  for (int d = lane; d < D; d += 64) { float t = r[d] - mean; v += t * t; }
  for (int off = 32; off; off >>= 1) v += __shfl_down(v, off);
  const float inv = rsqrtf(__shfl(v, 0) / (float)D + 1e-5f);
  float* orow = out + (size_t)wv * D;
  float a0 = 0.f, a1 = 0.f;
  for (int d = lane; d < D; d += 64) {
    const float o = (r[d] - mean) * inv * g[d] + b[d];
    orow[d] = o;
    if (outb) outb[(size_t)wv * D + d] = f2bf(o);
    if (gw) { a0 = fmaf(o, gw[2 * d], a0); a1 = fmaf(o, gw[2 * d + 1], a1); }
  }
  if (gw) {
    for (int off = 32; off; off >>= 1) { a0 += __shfl_down(a0, off); a1 += __shfl_down(a1, off); }
    if (lane == 0) {
      gamout[(size_t)wv * 2 + 0] = expf(a0 + gb[0]);
      gamout[(size_t)wv * 2 + 1] = expf(a1 + gb[1]);
    }
  }
}

// ---------------------------------------------------------------------------
// prep: bit-packed adj_cls. adjp[(b*M_+n)*17 + w] bit j = adj_cls[n][w*64+j].
// ---------------------------------------------------------------------------
__global__ __launch_bounds__(256) void adjp_k(const float* __restrict__ adj,
                                              unsigned long long* __restrict__ adjp)
{
  const int n = blockIdx.x;   // 0..1024
  const int b = blockIdx.y;
  const int wv = threadIdx.x >> 6, lane = threadIdx.x & 63;
  for (int w = wv; w < 17; w += 4) {
    const int m = w * 64 + lane;
    float av = 0.f;
    if (n == 0) av = (m == 0) ? 1.f : 0.f;
    else if (m >= 1 && m <= NSEQ) av = adj[((size_t)b * NSEQ + (n - 1)) * NSEQ + (m - 1)];
    const unsigned long long mask = __ballot(av != 0.f);
    if (lane == 0) adjp[((size_t)b * M_ + n) * 17 + w] = mask;
  }
}

// ---------------------------------------------------------------------------
// prep: Wt[n][k] = bf16(W[k][n])
// ---------------------------------------------------------------------------
__global__ void wtrans_k(const float* __restrict__ W, unsigned short* __restrict__ Wt,
                         int K, int N)
{
  __shared__ float t[32][33];
  const int k0 = blockIdx.x * 32, n0 = blockIdx.y * 32;
  const float* Wd = W + (size_t)blockIdx.z * K * N;
  unsigned short* Wtd = Wt + (size_t)blockIdx.z * K * N;
  for (int i = threadIdx.y; i < 32; i += 8)
    t[i][threadIdx.x] = Wd[(size_t)(k0 + i) * N + n0 + threadIdx.x];
  __syncthreads();
  for (int i = threadIdx.y; i < 32; i += 8)
    Wtd[(size_t)(n0 + i) * K + k0 + threadIdx.x] = f2bf(t[threadIdx.x][i]);
}

// ---------------------------------------------------------------------------
// bf16 MFMA flash attention (R11/R12 best): one tile/block, grid (8,17,8);
// bit-packed adj (4x 8B broadcast loads + bit test per element).
// No online softmax (scores bounded): p=exp(s), l per-lane, butterfly at end.
// sVt swizzle: elem (m, d) at sVt[d][(((m>>3) ^ ((d>>3)&7))*8) | (m&7)].
// sP  swizzle: P[q][key]  at sP[q][(((key>>3) ^ (q&7))*8) | (key&7)].
// NOTE (R13/R14 lessons): this kernel tolerates ZERO extra register
// pressure — LN fusion (R13) and register prefetch (R14, spilled to
// scratch at the 100-VGPR launch_bounds target) both regressed.
// ---------------------------------------------------------------------------
__global__ __launch_bounds__(256) void attn_mfma_k(
    const unsigned short* __restrict__ qkv, const float* __restrict__ gamma,
    const unsigned long long* __restrict__ adjp, const unsigned short* __restrict__ vt,
    unsigned short* __restrict__ o)
{
  __shared__ unsigned short sK[64][136];   // keys row-major, pad 8
  __shared__ unsigned short sVt[128][72];  // transposed V, swizzled
  __shared__ unsigned short sP[64][72];    // P, swizzled

  const int hh = blockIdx.x, qt = blockIdx.y, b = blockIdx.z;
  const int tid = threadIdx.x;
  const int w = tid >> 6;
  const int lane = tid & 63;
  const int col = lane & 15;
  const int quad = lane >> 4;
  const int n0 = qt * 64;
  const int qbase = n0 + w * 16;
  const float scale = 0.088388347648318447f;  // 128^-0.5

  // Q fragments (registers, direct global)
  bf16x8 aQ[4];
  {
    const int qrow = min(qbase + col, 1024);
    const unsigned short* qp = qkv + ((size_t)(b * M_ + qrow)) * QKV3 + hh * DIMC + quad * 8;
#pragma unroll
    for (int c = 0; c < 4; ++c) aQ[c] = *(const bf16x8*)(qp + c * 32);
  }
  float g0[4], g1[4];
  size_t adjo[4];
#pragma unroll
  for (int r = 0; r < 4; ++r) {
    const int nc = min(qbase + quad * 4 + r, 1024);
    g0[r] = gamma[(size_t)(b * M_ + nc) * 2 + 0] * scale;
    g1[r] = gamma[(size_t)(b * M_ + nc) * 2 + 1];
    adjo[r] = ((size_t)b * M_ + nc) * 17;
  }

  float l_i[4] = {0.f, 0.f, 0.f, 0.f};
  f32x4 Oacc[8];
#pragma unroll
  for (int t = 0; t < 8; ++t) Oacc[t] = (f32x4){0.f, 0.f, 0.f, 0.f};

  const size_t vtbase = ((size_t)(b * NHEADS + hh)) * DIMC * ACS;

  for (int kt = 0; kt < 17; ++kt) {
    const int m0 = kt * 64;
    __syncthreads();
    // stage K rows (vector) + Vt rows (vector, swizzled cols)
#pragma unroll
    for (int l = 0; l < 4; ++l) {
      const int idx = l * 256 + tid;
      {
        const int m = idx >> 4, c = idx & 15;
        const int gm = m0 + m;
        uint4 kv = make_uint4(0u, 0u, 0u, 0u);
        if (gm < M_) kv = *(const uint4*)(qkv + ((size_t)(b * M_ + gm)) * QKV3 + 1024 + hh * DIMC + c * 8);
        *(uint4*)&sK[m][c * 8] = kv;
      }
      {
        const int d = idx >> 3, mc = idx & 7;
        const uint4 vv = *(const uint4*)(vt + vtbase + (size_t)d * ACS + m0 + mc * 8);
        const int swc = mc ^ ((d >> 3) & 7);
        *(uint4*)&sVt[d][swc * 8] = vv;
      }
    }
    __syncthreads();

    // per-row adj bitmask for this k-tile (broadcast load, 8 B per row)
    unsigned long long mk[4];
#pragma unroll
    for (int r = 0; r < 4; ++r) mk[r] = adjp[adjo[r] + kt];

    // S = Q K^T
    f32x4 Sacc[4];
#pragma unroll
    for (int t = 0; t < 4; ++t) Sacc[t] = (f32x4){0.f, 0.f, 0.f, 0.f};
#pragma unroll
    for (int t = 0; t < 4; ++t) {
#pragma unroll
      for (int c = 0; c < 4; ++c) {
        const bf16x8 bK = *(const bf16x8*)&sK[t * 16 + col][c * 32 + quad * 8];
        Sacc[t] = __builtin_amdgcn_mfma_f32_16x16x32_bf16(aQ[c], bK, Sacc[t], 0, 0, 0);
      }
    }

    // p = exp(g0*S + (bit ? g1 : 0)); write P to LDS, acc l
#pragma unroll
    for (int t = 0; t < 4; ++t) {
      const int m = m0 + t * 16 + col;
      const bool mv = (m < M_);
      const int chb = t * 2 + (col >> 3);
      const int sh = t * 16 + col;
#pragma unroll
      for (int r = 0; r < 4; ++r) {
        const float bias = ((mk[r] >> sh) & 1ull) ? g1[r] : 0.f;
        const float s = fmaf(g0[r], Sacc[t][r], bias);
        const float pv = mv ? __expf(s) : 0.f;
        l_i[r] += pv;
        const int ql = w * 16 + quad * 4 + r;
        sP[ql][((chb ^ (ql & 7)) * 8) + (col & 7)] = f2bf(pv);
      }
    }

    // O += P V (own-wave P rows; swizzled reads, no barrier)
#pragma unroll
    for (int ch = 0; ch < 2; ++ch) {
      const int r0a = w * 16 + col;
      const bf16x8 aP = *(const bf16x8*)&sP[r0a][(((ch * 4 + quad) ^ (col & 7)) * 8)];
#pragma unroll
      for (int t = 0; t < 8; ++t) {
        const int pc = (ch * 4 + quad) ^ ((t * 2 + (col >> 3)) & 7);
        const bf16x8 bV = *(const bf16x8*)&sVt[t * 16 + col][pc * 8];
        Oacc[t] = __builtin_amdgcn_mfma_f32_16x16x32_bf16(aP, bV, Oacc[t], 0, 0, 0);
      }
    }
  }

  // epilogue: reduce l across the 16-lane col group, O /= l, bf16 out
#pragma unroll
  for (int r = 0; r < 4; ++r) {
    float s = l_i[r];
    s += __shfl_xor(s, 1);
    s += __shfl_xor(s, 2);
    s += __shfl_xor(s, 4);
    s += __shfl_xor(s, 8);
    const int n = qbase + quad * 4 + r;
    if (n < M_) {
      const float invl = 1.f / s;
      unsigned short* orow = o + ((size_t)(b * M_ + n)) * (NHEADS * DIMC) + hh * DIMC + col;
#pragma unroll
      for (int t = 0; t < 8; ++t) orow[t * 16] = f2bf(Oacc[t][r] * invl);
    }
  }
}

// ---------------------------------------------------------------------------
// Fused head: extract cls + LN + head_w + 3x gelu-proj + LN + proj_w4.
// ---------------------------------------------------------------------------
__global__ __launch_bounds__(256) void head_fused_k(
    const float* __restrict__ x,
    const float* __restrict__ hlg, const float* __restrict__ hlb,
    const float* __restrict__ hw, const float* __restrict__ hb,
    const float* __restrict__ pw1, const float* __restrict__ pb1,
    const float* __restrict__ pw2, const float* __restrict__ pb2,
    const float* __restrict__ pw3, const float* __restrict__ pb3,
    const float* __restrict__ plg, const float* __restrict__ plb,
    const float* __restrict__ pw4, const float* __restrict__ pb4,
    float* __restrict__ out_c, float* __restrict__ out_p)
{
  __shared__ float sA[8][128];
  __shared__ float sB[8][128];
  const int tid = threadIdx.x;

  for (int i = tid; i < 8 * 128; i += 256) {
    const int bb = i >> 7, d = i & 127;
    sA[bb][d] = x[(size_t)bb * M_ * DIMC + d];
  }
  __syncthreads();
  if (tid < 8) {
    float m = 0.f;
    for (int d = 0; d < 128; ++d) m += sA[tid][d];
    m *= (1.f / 128.f);
    float v = 0.f;
    for (int d = 0; d < 128; ++d) { const float t = sA[tid][d] - m; v += t * t; }
    const float inv = rsqrtf(v * (1.f / 128.f) + 1e-5f);
    for (int d = 0; d < 128; ++d) sA[tid][d] = (sA[tid][d] - m) * inv * hlg[d] + hlb[d];
  }
  __syncthreads();
  {
    const int j = tid & 127, rb = (tid >> 7) * 4;
    float acc[4];
#pragma unroll
    for (int r = 0; r < 4; ++r) acc[r] = hb[j];
    for (int k = 0; k < 128; ++k) {
      const float wv = hw[k * 128 + j];
#pragma unroll
      for (int r = 0; r < 4; ++r) acc[r] = fmaf(sA[rb + r][k], wv, acc[r]);
    }
#pragma unroll
    for (int r = 0; r < 4; ++r) { sB[rb + r][j] = acc[r]; out_c[(rb + r) * 128 + j] = acc[r]; }
  }
  __syncthreads();
  const float* Ws[3] = {pw1, pw2, pw3};
  const float* Bs[3] = {pb1, pb2, pb3};
  for (int s = 0; s < 3; ++s) {
    const float (*src)[128] = (s & 1) ? sA : sB;
    float (*dst)[128] = (s & 1) ? sB : sA;
    const int j = tid & 127, rb = (tid >> 7) * 4;
    float acc[4];
#pragma unroll
    for (int r = 0; r < 4; ++r) acc[r] = Bs[s][j];
    for (int k = 0; k < 128; ++k) {
      const float wv = Ws[s][k * 128 + j];
#pragma unroll
      for (int r = 0; r < 4; ++r) acc[r] = fmaf(src[rb + r][k], wv, acc[r]);
    }
#pragma unroll
    for (int r = 0; r < 4; ++r) dst[rb + r][j] = gelu_f(acc[r]);
    __syncthreads();
  }
  if (tid < 8) {
    float m = 0.f;
    for (int d = 0; d < 128; ++d) m += sA[tid][d];
    m *= (1.f / 128.f);
    float v = 0.f;
    for (int d = 0; d < 128; ++d) { const float t = sA[tid][d] - m; v += t * t; }
    const float inv = rsqrtf(v * (1.f / 128.f) + 1e-5f);
    for (int d = 0; d < 128; ++d) sA[tid][d] = (sA[tid][d] - m) * inv * plg[d] + plb[d];
  }
  __syncthreads();
  for (int j = tid; j < 1000; j += 256) {
    float acc[8];
#pragma unroll
    for (int bb = 0; bb < 8; ++bb) acc[bb] = pb4[j];
    for (int k = 0; k < 128; ++k) {
      const float wv = pw4[(size_t)k * 1000 + j];
#pragma unroll
      for (int bb = 0; bb < 8; ++bb) acc[bb] = fmaf(sA[bb][k], wv, acc[bb]);
    }
#pragma unroll
    for (int bb = 0; bb < 8; ++bb) out_p[bb * 1000 + j] = acc[bb];
  }
}

// ---------------------------------------------------------------------------
__global__ void fill_cls_k(const float* __restrict__ cls, float* __restrict__ x)
{
  x[(size_t)blockIdx.x * M_ * DIMC + threadIdx.x] = cls[threadIdx.x];
}

// ---------------------------------------------------------------------------
extern "C" void kernel_launch(void* const* d_in, const int* in_sizes, int n_in,
                              void* d_out, int out_size, void* d_ws, size_t ws_size,
                              hipStream_t stream)
{
  (void)in_sizes; (void)n_in; (void)out_size; (void)ws_size;
  const float* node_feat = (const float*)d_in[0];
  const float* adj       = (const float*)d_in[1];
  const float* lapl      = (const float*)d_in[2];
  const float* cls_token = (const float*)d_in[3];
  const float* pe_w1 = (const float*)d_in[4];
  const float* pe_b1 = (const float*)d_in[5];
  const float* pe_w2 = (const float*)d_in[6];
  const float* pe_b2 = (const float*)d_in[7];
  const float* pe_w3 = (const float*)d_in[8];
  const float* pe_b3 = (const float*)d_in[9];
  const float* pe_lng = (const float*)d_in[10];
  const float* pe_lnb = (const float*)d_in[11];
  const float* pe_w4 = (const float*)d_in[12];
  const float* pe_b4 = (const float*)d_in[13];
  const float* blk_ln1_g = (const float*)d_in[14];
  const float* blk_ln1_b = (const float*)d_in[15];
  const float* blk_qkv_w = (const float*)d_in[16];
  const float* blk_proj_w = (const float*)d_in[17];
  const float* blk_proj_b = (const float*)d_in[18];
  const float* blk_gamma_w = (const float*)d_in[19];
  const float* blk_gamma_b = (const float*)d_in[20];
  const float* blk_ln2_g = (const float*)d_in[21];
  const float* blk_ln2_b = (const float*)d_in[22];
  const float* blk_mlp_w1 = (const float*)d_in[23];
  const float* blk_mlp_b1 = (const float*)d_in[24];
  const float* blk_mlp_w2 = (const float*)d_in[25];
  const float* blk_mlp_b2 = (const float*)d_in[26];
  const float* head_lng = (const float*)d_in[27];
  const float* head_lnb = (const float*)d_in[28];
  const float* head_w = (const float*)d_in[29];
  const float* head_b = (const float*)d_in[30];
  const float* proj_w1 = (const float*)d_in[31];
  const float* proj_b1 = (const float*)d_in[32];
  const float* proj_w2 = (const float*)d_in[33];
  const float* proj_b2 = (const float*)d_in[34];
  const float* proj_w3 = (const float*)d_in[35];
  const float* proj_b3 = (const float*)d_in[36];
  const float* proj_lng = (const float*)d_in[37];
  const float* proj_lnb = (const float*)d_in[38];
  const float* proj_w4 = (const float*)d_in[39];
  const float* proj_b4 = (const float*)d_in[40];

  // ---- workspace layout ----
  float* ws   = (float*)d_ws;
  float* x    = ws;                        // 1,049,600 f
  float* h    = x + 1049600;               // 1,049,600 f
  float* gam  = h + 1049600;               // 16,400 f
  float* obuf = gam + 16400;               // 5,248,000 f region
  unsigned short* obufb = (unsigned short*)obuf;             // 8200*1024 bf16
  unsigned short* hidb  = (unsigned short*)(obuf + 4198400); // 8200*256 bf16
  float* sm  = obuf + 5248000;             // 8,192 f
  unsigned short* hb   = (unsigned short*)(sm + 8192);       // 8200*128 bf16
  unsigned short* qkv  = hb + 1049600;     // 25,190,400 us
  unsigned long long* adjp = (unsigned long long*)(qkv + 25190400);  // 139,400 u64
  unsigned short* vt   = (unsigned short*)(adjp + 139400 + 88);      // 8,912,896 us
  unsigned short* qkvWt = vt + 8912896;    // 5*393216
  unsigned short* projWt = qkvWt + 5 * 393216;
  unsigned short* mlp1Wt = projWt + 5 * 131072;
  unsigned short* mlp2Wt = mlp1Wt + 5 * 32768;

  float* out_c = (float*)d_out;            // (8,128)
  float* out_p = out_c + NB * DIMC;        // (8,1000)

  // ---- prep ----
  adjp_k<<<dim3(M_, NB), 256, 0, stream>>>(adj, adjp);
  wtrans_k<<<dim3(4, 96, 5), dim3(32, 8), 0, stream>>>(blk_qkv_w, qkvWt, 128, 3072);
  wtrans_k<<<dim3(32, 4, 5), dim3(32, 8), 0, stream>>>(blk_proj_w, projWt, 1024, 128);
  wtrans_k<<<dim3(4, 8, 5), dim3(32, 8), 0, stream>>>(blk_mlp_w1, mlp1Wt, 128, 256);
  wtrans_k<<<dim3(8, 4, 5), dim3(32, 8), 0, stream>>>(blk_mlp_w2, mlp2Wt, 256, 128);

  // ---- PE encoder ----
  pe_fused_k<<<512, 128, 0, stream>>>(node_feat, lapl, pe_w1, pe_b1, pe_w2, pe_b2,
                                      pe_w3, pe_b3, pe_lng, pe_lnb, pe_w4, pe_b4, x);
  fill_cls_k<<<NB, DIMC, 0, stream>>>(cls_token, x);

  // ---- transformer layers ----
  const int lnGrid = (ROWS * 64 + 255) / 256;  // 2050
  for (int i = 0; i < 5; ++i) {
    const float* ln1g = blk_ln1_g + i * DIMC;
    const float* ln1b = blk_ln1_b + i * DIMC;
    const float* pb   = blk_proj_b + i * DIMC;
    const float* gw   = blk_gamma_w + (size_t)i * DIMC * 2;
    const float* gb   = blk_gamma_b + i * 2;
    const float* ln2g = blk_ln2_g + i * DIMC;
    const float* ln2b = blk_ln2_b + i * DIMC;
    const float* mb1  = blk_mlp_b1 + i * 256;
    const float* mb2  = blk_mlp_b2 + i * DIMC;
    const unsigned short* qw = qkvWt + (size_t)i * 393216;
    const unsigned short* pw = projWt + (size_t)i * 131072;
    const unsigned short* m1w = mlp1Wt + (size_t)i * 32768;
    const unsigned short* m2w = mlp2Wt + (size_t)i * 32768;

    ln_rows_k<<<lnGrid, 256, 0, stream>>>(x, h, hb, ln1g, ln1b, gw, gb, gam, ROWS, DIMC);
    mgemm128_k<1, 1><<<dim3(65, 24), 256, 0, stream>>>(hb, qw, nullptr, qkv, vt, ROWS, 128, 3072);
    attn_mfma_k<<<dim3(NHEADS, 17, NB), 256, 0, stream>>>(qkv, gam, adjp, vt, obufb);
    mgemm_k<0, 0, 1><<<dim3(129, 2), 256, 0, stream>>>(obufb, pw, pb, h, x, ROWS, 1024, 128);
    ln_rows_k<<<lnGrid, 256, 0, stream>>>(x, h, hb, ln2g, ln2b, nullptr, nullptr, nullptr, ROWS, DIMC);
    mgemm_k<1, 1, 0><<<dim3(129, 4), 256, 0, stream>>>(hb, m1w, mb1, nullptr, hidb, ROWS, 128, 256);
    mgemm_k<0, 0, 1><<<dim3(129, 2), 256, 0, stream>>>(hidb, m2w, mb2, h, x, ROWS, 256, 128);
  }

  // ---- fused head ----
  head_fused_k<<<1, 256, 0, stream>>>(x, head_lng, head_lnb, head_w, head_b,
                                      proj_w1, proj_b1, proj_w2, proj_b2,
                                      proj_w3, proj_b3, proj_lng, proj_lnb,
                                      proj_w4, proj_b4, out_c, out_p);
}

// Round 16
// 1563.632 us; speedup vs baseline: 1.1300x; 1.0247x over previous
//
#include <hip/hip_runtime.h>
#include <hip/hip_bf16.h>
#include <math.h>

// Problem constants
#define NB 8
#define NSEQ 1024
#define M_ 1025                 // NSEQ + 1 (cls)
#define ROWS (NB * M_)          // 8200
#define DIMC 128
#define NHEADS 8
#define QKV3 3072               // 3*8*128
#define PEROWS (NB * NSEQ)      // 8192
#define ACS 1088                // vt padded column stride

typedef __attribute__((ext_vector_type(8))) short bf16x8;
typedef __attribute__((ext_vector_type(4))) float f32x4;

__device__ __forceinline__ float gelu_f(float x) {
  return 0.5f * x * (1.f + erff(x * 0.70710678118654752440f));
}

__device__ __forceinline__ unsigned short f2bf(float f) {
  __hip_bfloat16 h = __float2bfloat16(f);
  return *reinterpret_cast<unsigned short*>(&h);
}

__device__ __forceinline__ float bf2f(unsigned short u) {
  union { unsigned int i; float f; } c;
  c.i = ((unsigned int)u) << 16;
  return c.f;
}

// ---------------------------------------------------------------------------
// Fused PE encoder (R12)
// ---------------------------------------------------------------------------
__global__ __launch_bounds__(128) void pe_fused_k(
    const float* __restrict__ nf, const float* __restrict__ lp,
    const float* __restrict__ w1, const float* __restrict__ b1,
    const float* __restrict__ w2, const float* __restrict__ b2,
    const float* __restrict__ w3, const float* __restrict__ b3,
    const float* __restrict__ lng, const float* __restrict__ lnb,
    const float* __restrict__ w4, const float* __restrict__ b4,
    float* __restrict__ x)
{
  __shared__ float sA[16][36];
  __shared__ float sB[16][72];
  __shared__ float sC[16][72];
  const int tid = threadIdx.x;
  const int r0 = blockIdx.x * 16;

  for (int i = tid; i < 16 * 35; i += 128) {
    const int r = i / 35, c = i - r * 35;
    const int gr = r0 + r;
    sA[r][c] = (c < 3) ? nf[(size_t)gr * 3 + c] : lp[(size_t)gr * 32 + (c - 3)];
  }
  __syncthreads();
  if (tid < 70) {
    float acc[16];
#pragma unroll
    for (int r = 0; r < 16; ++r) acc[r] = b1[tid];
    for (int k = 0; k < 35; ++k) {
      const float wv = w1[k * 70 + tid];
#pragma unroll
      for (int r = 0; r < 16; ++r) acc[r] = fmaf(sA[r][k], wv, acc[r]);
    }
#pragma unroll
    for (int r = 0; r < 16; ++r) sB[r][tid] = gelu_f(acc[r]);
  }
  __syncthreads();
  if (tid < 70) {
    float acc[16];
#pragma unroll
    for (int r = 0; r < 16; ++r) acc[r] = b2[tid];
    for (int k = 0; k < 70; ++k) {
      const float wv = w2[k * 70 + tid];
#pragma unroll
      for (int r = 0; r < 16; ++r) acc[r] = fmaf(sB[r][k], wv, acc[r]);
    }
#pragma unroll
    for (int r = 0; r < 16; ++r) sC[r][tid] = gelu_f(acc[r]);
  }
  __syncthreads();
  if (tid < 70) {
    float acc[16];
#pragma unroll
    for (int r = 0; r < 16; ++r) acc[r] = b3[tid];
    for (int k = 0; k < 70; ++k) {
      const float wv = w3[k * 70 + tid];
#pragma unroll
      for (int r = 0; r < 16; ++r) acc[r] = fmaf(sC[r][k], wv, acc[r]);
    }
#pragma unroll
    for (int r = 0; r < 16; ++r) sB[r][tid] = gelu_f(acc[r]);
  }
  __syncthreads();
  if (tid < 16) {
    float m = 0.f;
    for (int d = 0; d < 70; ++d) m += sB[tid][d];
    m *= (1.f / 70.f);
    float v = 0.f;
    for (int d = 0; d < 70; ++d) { const float t = sB[tid][d] - m; v += t * t; }
    const float inv = rsqrtf(v * (1.f / 70.f) + 1e-5f);
    for (int d = 0; d < 70; ++d) sB[tid][d] = (sB[tid][d] - m) * inv * lng[d] + lnb[d];
  }
  __syncthreads();
  {
    float acc[16];
#pragma unroll
    for (int r = 0; r < 16; ++r) acc[r] = b4[tid];
    for (int k = 0; k < 70; ++k) {
      const float wv = w4[k * 128 + tid];
#pragma unroll
      for (int r = 0; r < 16; ++r) acc[r] = fmaf(sB[r][k], wv, acc[r]);
    }
#pragma unroll
    for (int r = 0; r < 16; ++r) {
      const int gr = r0 + r;
      x[(size_t)(gr + gr / 1024 + 1) * DIMC + tid] = acc[r];
    }
  }
}

// ---------------------------------------------------------------------------
// bf16 MFMA GEMM, 64x64 tile (proj / mlp)
// ---------------------------------------------------------------------------
template<int ACT, int OBF, int RES>
__global__ __launch_bounds__(256) void mgemm_k(
    const unsigned short* __restrict__ Xb, const unsigned short* __restrict__ Wt,
    const float* __restrict__ bias, const float* __restrict__ res,
    void* __restrict__ outp, int rows, int K, int N)
{
  __shared__ unsigned short sX[64][72];
  __shared__ unsigned short sW[64][72];
  const int tid = threadIdx.x;
  const int w = tid >> 6, lane = tid & 63;
  const int col = lane & 15, quad = lane >> 4;
  const int r0 = blockIdx.x * 64, n0 = blockIdx.y * 64;
  const int lr = tid >> 2, lc = tid & 3;
  const int xrow = min(r0 + lr, rows - 1);
  const unsigned short* xsrc = Xb + (size_t)xrow * K + lc * 8;
  const unsigned short* wsrc = Wt + (size_t)(n0 + lr) * K + lc * 8;

  f32x4 acc[4];
#pragma unroll
  for (int t = 0; t < 4; ++t) acc[t] = (f32x4){0.f, 0.f, 0.f, 0.f};

  for (int k0 = 0; k0 < K; k0 += 64) {
    __syncthreads();
    *(uint4*)&sX[lr][lc * 8]      = *(const uint4*)(xsrc + k0);
    *(uint4*)&sX[lr][lc * 8 + 32] = *(const uint4*)(xsrc + k0 + 32);
    *(uint4*)&sW[lr][lc * 8]      = *(const uint4*)(wsrc + k0);
    *(uint4*)&sW[lr][lc * 8 + 32] = *(const uint4*)(wsrc + k0 + 32);
    __syncthreads();
    const bf16x8 aX0 = *(const bf16x8*)&sX[w * 16 + col][quad * 8];
    const bf16x8 aX1 = *(const bf16x8*)&sX[w * 16 + col][32 + quad * 8];
#pragma unroll
    for (int t = 0; t < 4; ++t) {
      const bf16x8 bW0 = *(const bf16x8*)&sW[t * 16 + col][quad * 8];
      const bf16x8 bW1 = *(const bf16x8*)&sW[t * 16 + col][32 + quad * 8];
      acc[t] = __builtin_amdgcn_mfma_f32_16x16x32_bf16(aX0, bW0, acc[t], 0, 0, 0);
      acc[t] = __builtin_amdgcn_mfma_f32_16x16x32_bf16(aX1, bW1, acc[t], 0, 0, 0);
    }
  }
  const int gr_base = r0 + w * 16 + quad * 4;
#pragma unroll
  for (int t = 0; t < 4; ++t) {
    const int n = n0 + t * 16 + col;
    const float bv = bias ? bias[n] : 0.f;
#pragma unroll
    for (int r = 0; r < 4; ++r) {
      const int gr = gr_base + r;
      if (gr < rows) {
        float v = acc[t][r] + bv;
        if (ACT) v = gelu_f(v);
        if (RES) v += res[(size_t)gr * N + n];
        if (OBF) ((unsigned short*)outp)[(size_t)gr * N + n] = f2bf(v);
        else     ((float*)outp)[(size_t)gr * N + n] = v;
      }
    }
  }
}

// ---------------------------------------------------------------------------
// bf16 MFMA GEMM, 128x128 tile (QKV), with fused V-transpose epilogue
// ---------------------------------------------------------------------------
template<int OBF, int VT>
__global__ __launch_bounds__(256) void mgemm128_k(
    const unsigned short* __restrict__ Xb, const unsigned short* __restrict__ Wt,
    const float* __restrict__ bias, void* __restrict__ outp,
    unsigned short* __restrict__ vtp, int rows, int K, int N)
{
  __shared__ unsigned short sX[128][72];
  __shared__ unsigned short sW[128][72];
  const int tid = threadIdx.x;
  const int w = tid >> 6, lane = tid & 63;
  const int col = lane & 15, quad = lane >> 4;
  const int wr = w >> 1, wc = w & 1;
  const int r0 = blockIdx.x * 128, n0 = blockIdx.y * 128;

  f32x4 acc[4][4];
#pragma unroll
  for (int i = 0; i < 4; ++i)
#pragma unroll
    for (int j = 0; j < 4; ++j) acc[i][j] = (f32x4){0.f, 0.f, 0.f, 0.f};

  for (int k0 = 0; k0 < K; k0 += 64) {
    __syncthreads();
#pragma unroll
    for (int l = 0; l < 4; ++l) {
      const int idx = l * 256 + tid;
      const int row = idx >> 3, c = idx & 7;
      const int xrow = min(r0 + row, rows - 1);
      *(uint4*)&sX[row][c * 8] = *(const uint4*)(Xb + (size_t)xrow * K + k0 + c * 8);
      *(uint4*)&sW[row][c * 8] = *(const uint4*)(Wt + (size_t)(n0 + row) * K + k0 + c * 8);
    }
    __syncthreads();
    bf16x8 aX[4][2];
#pragma unroll
    for (int i = 0; i < 4; ++i) {
      aX[i][0] = *(const bf16x8*)&sX[wr * 64 + i * 16 + col][quad * 8];
      aX[i][1] = *(const bf16x8*)&sX[wr * 64 + i * 16 + col][32 + quad * 8];
    }
#pragma unroll
    for (int j = 0; j < 4; ++j) {
      const bf16x8 b0 = *(const bf16x8*)&sW[wc * 64 + j * 16 + col][quad * 8];
      const bf16x8 b1 = *(const bf16x8*)&sW[wc * 64 + j * 16 + col][32 + quad * 8];
#pragma unroll
      for (int i = 0; i < 4; ++i) {
        acc[i][j] = __builtin_amdgcn_mfma_f32_16x16x32_bf16(aX[i][0], b0, acc[i][j], 0, 0, 0);
        acc[i][j] = __builtin_amdgcn_mfma_f32_16x16x32_bf16(aX[i][1], b1, acc[i][j], 0, 0, 0);
      }
    }
  }
  const bool dovt = VT && (n0 >= 2048);
#pragma unroll
  for (int i = 0; i < 4; ++i) {
    const int gr_base = r0 + wr * 64 + i * 16 + quad * 4;
    int bb[4], mm[4];
    if (dovt) {
#pragma unroll
      for (int r = 0; r < 4; ++r) {
        const int gr = gr_base + r;
        bb[r] = gr / 1025;
        mm[r] = gr - bb[r] * 1025;
      }
    }
#pragma unroll
    for (int j = 0; j < 4; ++j) {
      const int n = n0 + wc * 64 + j * 16 + col;
      const float bv = bias ? bias[n] : 0.f;
      const int hh = (n - 2048) >> 7;
      const int d  = (n - 2048) & 127;
#pragma unroll
      for (int r = 0; r < 4; ++r) {
        const int gr = gr_base + r;
        if (gr < rows) {
          const float v = acc[i][j][r] + bv;
          const unsigned short bf = f2bf(v);
          if (OBF) ((unsigned short*)outp)[(size_t)gr * N + n] = bf;
          else     ((float*)outp)[(size_t)gr * N + n] = v;
          if (dovt) vtp[(((size_t)(bb[r] * NHEADS + hh) * DIMC + d) * ACS) + mm[r]] = bf;
        }
      }
    }
  }
}

// ---------------------------------------------------------------------------
// Wave-per-row LayerNorm; optional bf16 shadow out; optional fused gamma
// ---------------------------------------------------------------------------
__global__ __launch_bounds__(256) void ln_rows_k(
    const float* __restrict__ in, float* __restrict__ out,
    unsigned short* __restrict__ outb,
    const float* __restrict__ g, const float* __restrict__ b,
    const float* __restrict__ gw, const float* __restrict__ gb,
    float* __restrict__ gamout, int rows, int D)
{
  const int wv = (blockIdx.x * blockDim.x + threadIdx.x) >> 6;
  const int lane = threadIdx.x & 63;
  if (wv >= rows) return;
  const float* r = in + (size_t)wv * D;
  float s = 0.f;
  for (int d = lane; d < D; d += 64) s += r[d];
  for (int off = 32; off; off >>= 1) s += __shfl_down(s, off);
  const float mean = __shfl(s, 0) / (float)D;
  float v = 0.f;
  for (int d = lane; d < D; d += 64) { float t = r[d] - mean; v += t * t; }
  for (int off = 32; off; off >>= 1) v += __shfl_down(v, off);
  const float inv = rsqrtf(__shfl(v, 0) / (float)D + 1e-5f);
  float* orow = out + (size_t)wv * D;
  float a0 = 0.f, a1 = 0.f;
  for (int d = lane; d < D; d += 64) {
    const float o = (r[d] - mean) * inv * g[d] + b[d];
    orow[d] = o;
    if (outb) outb[(size_t)wv * D + d] = f2bf(o);
    if (gw) { a0 = fmaf(o, gw[2 * d], a0); a1 = fmaf(o, gw[2 * d + 1], a1); }
  }
  if (gw) {
    for (int off = 32; off; off >>= 1) { a0 += __shfl_down(a0, off); a1 += __shfl_down(a1, off); }
    if (lane == 0) {
      gamout[(size_t)wv * 2 + 0] = expf(a0 + gb[0]);
      gamout[(size_t)wv * 2 + 1] = expf(a1 + gb[1]);
    }
  }
}

// ---------------------------------------------------------------------------
// prep: bit-packed adj_cls
// ---------------------------------------------------------------------------
__global__ __launch_bounds__(256) void adjp_k(const float* __restrict__ adj,
                                              unsigned long long* __restrict__ adjp)
{
  const int n = blockIdx.x;
  const int b = blockIdx.y;
  const int wv = threadIdx.x >> 6, lane = threadIdx.x & 63;
  for (int w = wv; w < 17; w += 4) {
    const int m = w * 64 + lane;
    float av = 0.f;
    if (n == 0) av = (m == 0) ? 1.f : 0.f;
    else if (m >= 1 && m <= NSEQ) av = adj[((size_t)b * NSEQ + (n - 1)) * NSEQ + (m - 1)];
    const unsigned long long mask = __ballot(av != 0.f);
    if (lane == 0) adjp[((size_t)b * M_ + n) * 17 + w] = mask;
  }
}

// ---------------------------------------------------------------------------
// prep: Wt[n][k] = bf16(W[k][n])
// ---------------------------------------------------------------------------
__global__ void wtrans_k(const float* __restrict__ W, unsigned short* __restrict__ Wt,
                         int K, int N)
{
  __shared__ float t[32][33];
  const int k0 = blockIdx.x * 32, n0 = blockIdx.y * 32;
  const float* Wd = W + (size_t)blockIdx.z * K * N;
  unsigned short* Wtd = Wt + (size_t)blockIdx.z * K * N;
  for (int i = threadIdx.y; i < 32; i += 8)
    t[i][threadIdx.x] = Wd[(size_t)(k0 + i) * N + n0 + threadIdx.x];
  __syncthreads();
  for (int i = threadIdx.y; i < 32; i += 8)
    Wtd[(size_t)(n0 + i) * K + k0 + threadIdx.x] = f2bf(t[threadIdx.x][i]);
}

// ---------------------------------------------------------------------------
// bf16 MFMA flash attention, 8-WAVE BLOCKS (512 thr), Q-tile 128, K-tile 64.
// grid (8=heads, 9=qtile, 8=batch). Per-wave state is IDENTICAL to R12
// (16 q-rows, Oacc[8], ~100 VGPR — the R5 failure held 2 tile contexts,
// this holds 1). Staging (64 K-rows + 128 Vt-rows) is now amortized over
// 2x the MFMA work, and LDS 54.3KB -> 2 blocks/CU x 8 waves = 16 waves/CU
// (vs 12). K/V L2 refetch across q-tiles: 17 -> 9 blocks per (hh,b).
// Bit-packed adj; no online softmax (scores bounded); sP own-wave rows.
// ---------------------------------------------------------------------------
__global__ __launch_bounds__(512) void attn_mfma_k(
    const unsigned short* __restrict__ qkv, const float* __restrict__ gamma,
    const unsigned long long* __restrict__ adjp, const unsigned short* __restrict__ vt,
    unsigned short* __restrict__ o)
{
  __shared__ unsigned short sK[64][136];   // keys row-major, pad 8
  __shared__ unsigned short sVt[128][72];  // transposed V, swizzled
  __shared__ unsigned short sP[128][72];   // P, swizzled; wave w owns rows 16w..16w+15

  const int hh = blockIdx.x, qt = blockIdx.y, b = blockIdx.z;
  const int tid = threadIdx.x;
  const int w = tid >> 6;                  // 0..7
  const int lane = tid & 63;
  const int col = lane & 15;
  const int quad = lane >> 4;
  const int n0 = qt * 128;
  const int qbase = n0 + w * 16;
  const float scale = 0.088388347648318447f;  // 128^-0.5

  // Q fragments (registers, direct global)
  bf16x8 aQ[4];
  {
    const int qrow = min(qbase + col, 1024);
    const unsigned short* qp = qkv + ((size_t)(b * M_ + qrow)) * QKV3 + hh * DIMC + quad * 8;
#pragma unroll
    for (int c = 0; c < 4; ++c) aQ[c] = *(const bf16x8*)(qp + c * 32);
  }
  float g0[4], g1[4];
  size_t adjo[4];
#pragma unroll
  for (int r = 0; r < 4; ++r) {
    const int nc = min(qbase + quad * 4 + r, 1024);
    g0[r] = gamma[(size_t)(b * M_ + nc) * 2 + 0] * scale;
    g1[r] = gamma[(size_t)(b * M_ + nc) * 2 + 1];
    adjo[r] = ((size_t)b * M_ + nc) * 17;
  }

  float l_i[4] = {0.f, 0.f, 0.f, 0.f};
  f32x4 Oacc[8];
#pragma unroll
  for (int t = 0; t < 8; ++t) Oacc[t] = (f32x4){0.f, 0.f, 0.f, 0.f};

  const size_t vtbase = ((size_t)(b * NHEADS + hh)) * DIMC * ACS;

  for (int kt = 0; kt < 17; ++kt) {
    const int m0 = kt * 64;
    __syncthreads();
    // stage K rows (vector) + Vt rows (vector, swizzled cols) — 512 threads
#pragma unroll
    for (int l = 0; l < 2; ++l) {
      const int idx = l * 512 + tid;
      {
        const int m = idx >> 4, c = idx & 15;
        const int gm = m0 + m;
        uint4 kv = make_uint4(0u, 0u, 0u, 0u);
        if (gm < M_) kv = *(const uint4*)(qkv + ((size_t)(b * M_ + gm)) * QKV3 + 1024 + hh * DIMC + c * 8);
        *(uint4*)&sK[m][c * 8] = kv;
      }
      {
        const int d = idx >> 3, mc = idx & 7;
        const uint4 vv = *(const uint4*)(vt + vtbase + (size_t)d * ACS + m0 + mc * 8);
        const int swc = mc ^ ((d >> 3) & 7);
        *(uint4*)&sVt[d][swc * 8] = vv;
      }
    }
    __syncthreads();

    // per-row adj bitmask for this k-tile
    unsigned long long mk[4];
#pragma unroll
    for (int r = 0; r < 4; ++r) mk[r] = adjp[adjo[r] + kt];

    // S = Q K^T
    f32x4 Sacc[4];
#pragma unroll
    for (int t = 0; t < 4; ++t) Sacc[t] = (f32x4){0.f, 0.f, 0.f, 0.f};
#pragma unroll
    for (int t = 0; t < 4; ++t) {
#pragma unroll
      for (int c = 0; c < 4; ++c) {
        const bf16x8 bK = *(const bf16x8*)&sK[t * 16 + col][c * 32 + quad * 8];
        Sacc[t] = __builtin_amdgcn_mfma_f32_16x16x32_bf16(aQ[c], bK, Sacc[t], 0, 0, 0);
      }
    }

    // p = exp(g0*S + (bit ? g1 : 0)); write P to LDS, acc l
#pragma unroll
    for (int t = 0; t < 4; ++t) {
      const int m = m0 + t * 16 + col;
      const bool mv = (m < M_);
      const int chb = t * 2 + (col >> 3);
      const int sh = t * 16 + col;
#pragma unroll
      for (int r = 0; r < 4; ++r) {
        const float bias = ((mk[r] >> sh) & 1ull) ? g1[r] : 0.f;
        const float s = fmaf(g0[r], Sacc[t][r], bias);
        const float pv = mv ? __expf(s) : 0.f;
        l_i[r] += pv;
        const int ql = w * 16 + quad * 4 + r;
        sP[ql][((chb ^ (ql & 7)) * 8) + (col & 7)] = f2bf(pv);
      }
    }

    // O += P V (own-wave P rows; swizzled reads, no barrier)
#pragma unroll
    for (int ch = 0; ch < 2; ++ch) {
      const int r0a = w * 16 + col;
      const bf16x8 aP = *(const bf16x8*)&sP[r0a][(((ch * 4 + quad) ^ (col & 7)) * 8)];
#pragma unroll
      for (int t = 0; t < 8; ++t) {
        const int pc = (ch * 4 + quad) ^ ((t * 2 + (col >> 3)) & 7);
        const bf16x8 bV = *(const bf16x8*)&sVt[t * 16 + col][pc * 8];
        Oacc[t] = __builtin_amdgcn_mfma_f32_16x16x32_bf16(aP, bV, Oacc[t], 0, 0, 0);
      }
    }
  }

  // epilogue: reduce l across the 16-lane col group, O /= l, bf16 out
#pragma unroll
  for (int r = 0; r < 4; ++r) {
    float s = l_i[r];
    s += __shfl_xor(s, 1);
    s += __shfl_xor(s, 2);
    s += __shfl_xor(s, 4);
    s += __shfl_xor(s, 8);
    const int n = qbase + quad * 4 + r;
    if (n < M_) {
      const float invl = 1.f / s;
      unsigned short* orow = o + ((size_t)(b * M_ + n)) * (NHEADS * DIMC) + hh * DIMC + col;
#pragma unroll
      for (int t = 0; t < 8; ++t) orow[t * 16] = f2bf(Oacc[t][r] * invl);
    }
  }
}

// ---------------------------------------------------------------------------
// Fused head (R12)
// ---------------------------------------------------------------------------
__global__ __launch_bounds__(256) void head_fused_k(
    const float* __restrict__ x,
    const float* __restrict__ hlg, const float* __restrict__ hlb,
    const float* __restrict__ hw, const float* __restrict__ hb,
    const float* __restrict__ pw1, const float* __restrict__ pb1,
    const float* __restrict__ pw2, const float* __restrict__ pb2,
    const float* __restrict__ pw3, const float* __restrict__ pb3,
    const float* __restrict__ plg, const float* __restrict__ plb,
    const float* __restrict__ pw4, const float* __restrict__ pb4,
    float* __restrict__ out_c, float* __restrict__ out_p)
{
  __shared__ float sA[8][128];
  __shared__ float sB[8][128];
  const int tid = threadIdx.x;

  for (int i = tid; i < 8 * 128; i += 256) {
    const int bb = i >> 7, d = i & 127;
    sA[bb][d] = x[(size_t)bb * M_ * DIMC + d];
  }
  __syncthreads();
  if (tid < 8) {
    float m = 0.f;
    for (int d = 0; d < 128; ++d) m += sA[tid][d];
    m *= (1.f / 128.f);
    float v = 0.f;
    for (int d = 0; d < 128; ++d) { const float t = sA[tid][d] - m; v += t * t; }
    const float inv = rsqrtf(v * (1.f / 128.f) + 1e-5f);
    for (int d = 0; d < 128; ++d) sA[tid][d] = (sA[tid][d] - m) * inv * hlg[d] + hlb[d];
  }
  __syncthreads();
  {
    const int j = tid & 127, rb = (tid >> 7) * 4;
    float acc[4];
#pragma unroll
    for (int r = 0; r < 4; ++r) acc[r] = hb[j];
    for (int k = 0; k < 128; ++k) {
      const float wv = hw[k * 128 + j];
#pragma unroll
      for (int r = 0; r < 4; ++r) acc[r] = fmaf(sA[rb + r][k], wv, acc[r]);
    }
#pragma unroll
    for (int r = 0; r < 4; ++r) { sB[rb + r][j] = acc[r]; out_c[(rb + r) * 128 + j] = acc[r]; }
  }
  __syncthreads();
  const float* Ws[3] = {pw1, pw2, pw3};
  const float* Bs[3] = {pb1, pb2, pb3};
  for (int s = 0; s < 3; ++s) {
    const float (*src)[128] = (s & 1) ? sA : sB;
    float (*dst)[128] = (s & 1) ? sB : sA;
    const int j = tid & 127, rb = (tid >> 7) * 4;
    float acc[4];
#pragma unroll
    for (int r = 0; r < 4; ++r) acc[r] = Bs[s][j];
    for (int k = 0; k < 128; ++k) {
      const float wv = Ws[s][k * 128 + j];
#pragma unroll
      for (int r = 0; r < 4; ++r) acc[r] = fmaf(src[rb + r][k], wv, acc[r]);
    }
#pragma unroll
    for (int r = 0; r < 4; ++r) dst[rb + r][j] = gelu_f(acc[r]);
    __syncthreads();
  }
  if (tid < 8) {
    float m = 0.f;
    for (int d = 0; d < 128; ++d) m += sA[tid][d];
    m *= (1.f / 128.f);
    float v = 0.f;
    for (int d = 0; d < 128; ++d) { const float t = sA[tid][d] - m; v += t * t; }
    const float inv = rsqrtf(v * (1.f / 128.f) + 1e-5f);
    for (int d = 0; d < 128; ++d) sA[tid][d] = (sA[tid][d] - m) * inv * plg[d] + plb[d];
  }
  __syncthreads();
  for (int j = tid; j < 1000; j += 256) {
    float acc[8];
#pragma unroll
    for (int bb = 0; bb < 8; ++bb) acc[bb] = pb4[j];
    for (int k = 0; k < 128; ++k) {
      const float wv = pw4[(size_t)k * 1000 + j];
#pragma unroll
      for (int bb = 0; bb < 8; ++bb) acc[bb] = fmaf(sA[bb][k], wv, acc[bb]);
    }
#pragma unroll
    for (int bb = 0; bb < 8; ++bb) out_p[bb * 1000 + j] = acc[bb];
  }
}

// ---------------------------------------------------------------------------
__global__ void fill_cls_k(const float* __restrict__ cls, float* __restrict__ x)
{
  x[(size_t)blockIdx.x * M_ * DIMC + threadIdx.x] = cls[threadIdx.x];
}

// ---------------------------------------------------------------------------
extern "C" void kernel_launch(void* const* d_in, const int* in_sizes, int n_in,
                              void* d_out, int out_size, void* d_ws, size_t ws_size,
                              hipStream_t stream)
{
  (void)in_sizes; (void)n_in; (void)out_size; (void)ws_size;
  const float* node_feat = (const float*)d_in[0];
  const float* adj       = (const float*)d_in[1];
  const float* lapl      = (const float*)d_in[2];
  const float* cls_token = (const float*)d_in[3];
  const float* pe_w1 = (const float*)d_in[4];
  const float* pe_b1 = (const float*)d_in[5];
  const float* pe_w2 = (const float*)d_in[6];
  const float* pe_b2 = (const float*)d_in[7];
  const float* pe_w3 = (const float*)d_in[8];
  const float* pe_b3 = (const float*)d_in[9];
  const float* pe_lng = (const float*)d_in[10];
  const float* pe_lnb = (const float*)d_in[11];
  const float* pe_w4 = (const float*)d_in[12];
  const float* pe_b4 = (const float*)d_in[13];
  const float* blk_ln1_g = (const float*)d_in[14];
  const float* blk_ln1_b = (const float*)d_in[15];
  const float* blk_qkv_w = (const float*)d_in[16];
  const float* blk_proj_w = (const float*)d_in[17];
  const float* blk_proj_b = (const float*)d_in[18];
  const float* blk_gamma_w = (const float*)d_in[19];
  const float* blk_gamma_b = (const float*)d_in[20];
  const float* blk_ln2_g = (const float*)d_in[21];
  const float* blk_ln2_b = (const float*)d_in[22];
  const float* blk_mlp_w1 = (const float*)d_in[23];
  const float* blk_mlp_b1 = (const float*)d_in[24];
  const float* blk_mlp_w2 = (const float*)d_in[25];
  const float* blk_mlp_b2 = (const float*)d_in[26];
  const float* head_lng = (const float*)d_in[27];
  const float* head_lnb = (const float*)d_in[28];
  const float* head_w = (const float*)d_in[29];
  const float* head_b = (const float*)d_in[30];
  const float* proj_w1 = (const float*)d_in[31];
  const float* proj_b1 = (const float*)d_in[32];
  const float* proj_w2 = (const float*)d_in[33];
  const float* proj_b2 = (const float*)d_in[34];
  const float* proj_w3 = (const float*)d_in[35];
  const float* proj_b3 = (const float*)d_in[36];
  const float* proj_lng = (const float*)d_in[37];
  const float* proj_lnb = (const float*)d_in[38];
  const float* proj_w4 = (const float*)d_in[39];
  const float* proj_b4 = (const float*)d_in[40];

  // ---- workspace layout ----
  float* ws   = (float*)d_ws;
  float* x    = ws;                        // 1,049,600 f
  float* h    = x + 1049600;               // 1,049,600 f
  float* gam  = h + 1049600;               // 16,400 f
  float* obuf = gam + 16400;               // 5,248,000 f region
  unsigned short* obufb = (unsigned short*)obuf;             // 8200*1024 bf16
  unsigned short* hidb  = (unsigned short*)(obuf + 4198400); // 8200*256 bf16
  float* sm  = obuf + 5248000;             // 8,192 f
  unsigned short* hb   = (unsigned short*)(sm + 8192);       // 8200*128 bf16
  unsigned short* qkv  = hb + 1049600;     // 25,190,400 us
  unsigned long long* adjp = (unsigned long long*)(qkv + 25190400);  // 139,400 u64
  unsigned short* vt   = (unsigned short*)(adjp + 139400 + 88);      // 8,912,896 us
  unsigned short* qkvWt = vt + 8912896;    // 5*393216
  unsigned short* projWt = qkvWt + 5 * 393216;
  unsigned short* mlp1Wt = projWt + 5 * 131072;
  unsigned short* mlp2Wt = mlp1Wt + 5 * 32768;

  float* out_c = (float*)d_out;            // (8,128)
  float* out_p = out_c + NB * DIMC;        // (8,1000)

  // ---- prep ----
  adjp_k<<<dim3(M_, NB), 256, 0, stream>>>(adj, adjp);
  wtrans_k<<<dim3(4, 96, 5), dim3(32, 8), 0, stream>>>(blk_qkv_w, qkvWt, 128, 3072);
  wtrans_k<<<dim3(32, 4, 5), dim3(32, 8), 0, stream>>>(blk_proj_w, projWt, 1024, 128);
  wtrans_k<<<dim3(4, 8, 5), dim3(32, 8), 0, stream>>>(blk_mlp_w1, mlp1Wt, 128, 256);
  wtrans_k<<<dim3(8, 4, 5), dim3(32, 8), 0, stream>>>(blk_mlp_w2, mlp2Wt, 256, 128);

  // ---- PE encoder ----
  pe_fused_k<<<512, 128, 0, stream>>>(node_feat, lapl, pe_w1, pe_b1, pe_w2, pe_b2,
                                      pe_w3, pe_b3, pe_lng, pe_lnb, pe_w4, pe_b4, x);
  fill_cls_k<<<NB, DIMC, 0, stream>>>(cls_token, x);

  // ---- transformer layers ----
  const int lnGrid = (ROWS * 64 + 255) / 256;  // 2050
  for (int i = 0; i < 5; ++i) {
    const float* ln1g = blk_ln1_g + i * DIMC;
    const float* ln1b = blk_ln1_b + i * DIMC;
    const float* pb   = blk_proj_b + i * DIMC;
    const float* gw   = blk_gamma_w + (size_t)i * DIMC * 2;
    const float* gb   = blk_gamma_b + i * 2;
    const float* ln2g = blk_ln2_g + i * DIMC;
    const float* ln2b = blk_ln2_b + i * DIMC;
    const float* mb1  = blk_mlp_b1 + i * 256;
    const float* mb2  = blk_mlp_b2 + i * DIMC;
    const unsigned short* qw = qkvWt + (size_t)i * 393216;
    const unsigned short* pw = projWt + (size_t)i * 131072;
    const unsigned short* m1w = mlp1Wt + (size_t)i * 32768;
    const unsigned short* m2w = mlp2Wt + (size_t)i * 32768;

    ln_rows_k<<<lnGrid, 256, 0, stream>>>(x, h, hb, ln1g, ln1b, gw, gb, gam, ROWS, DIMC);
    mgemm128_k<1, 1><<<dim3(65, 24), 256, 0, stream>>>(hb, qw, nullptr, qkv, vt, ROWS, 128, 3072);
    attn_mfma_k<<<dim3(NHEADS, 9, NB), 512, 0, stream>>>(qkv, gam, adjp, vt, obufb);
    mgemm_k<0, 0, 1><<<dim3(129, 2), 256, 0, stream>>>(obufb, pw, pb, h, x, ROWS, 1024, 128);
    ln_rows_k<<<lnGrid, 256, 0, stream>>>(x, h, hb, ln2g, ln2b, nullptr, nullptr, nullptr, ROWS, DIMC);
    mgemm_k<1, 1, 0><<<dim3(129, 4), 256, 0, stream>>>(hb, m1w, mb1, nullptr, hidb, ROWS, 128, 256);
    mgemm_k<0, 0, 1><<<dim3(129, 2), 256, 0, stream>>>(hidb, m2w, mb2, h, x, ROWS, 256, 128);
  }

  // ---- fused head ----
  head_fused_k<<<1, 256, 0, stream>>>(x, head_lng, head_lnb, head_w, head_b,
                                      proj_w1, proj_b1, proj_w2, proj_b2,
                                      proj_w3, proj_b3, proj_lng, proj_lnb,
                                      proj_w4, proj_b4, out_c, out_p);
}